// Round 6
// baseline (782.748 us; speedup 1.0000x reference)
//
#include <hip/hip_runtime.h>
#include <math.h>

// Problem constants: B=2, N=2048, D=1024, H=16, HD=64, C=4

typedef __attribute__((ext_vector_type(8))) short s8v;
typedef __attribute__((ext_vector_type(4))) short s4v;
typedef __attribute__((ext_vector_type(4))) float f4v;

#define L2E 1.44269504088896340736f

__device__ __forceinline__ unsigned short f2bf(float x) {
    union { float f; unsigned u; } v; v.f = x;
    unsigned r = v.u + 0x7FFF + ((v.u >> 16) & 1);
    return (unsigned short)(r >> 16);
}
__device__ __forceinline__ float bf2f(unsigned short h) {
    union { unsigned u; float f; } v; v.u = ((unsigned)h) << 16;
    return v.f;
}
__device__ __forceinline__ f4v mfma32(s8v a, s8v b, f4v c) {
    return __builtin_amdgcn_mfma_f32_16x16x32_bf16(a, b, c, 0, 0, 0);
}
__device__ __forceinline__ void gl_lds16(const void* g, void* l) {
    __builtin_amdgcn_global_load_lds(
        (const __attribute__((address_space(1))) unsigned*)g,
        (__attribute__((address_space(3))) unsigned*)l, 16, 0, 0);
}
// raw v_exp_f32: 1 instr, no OCML range-fixup wrapper
__device__ __forceinline__ float exp2g(float x) {
    float r; asm("v_exp_f32 %0, %1" : "=v"(r) : "v"(x)); return r;
}

// ---------------------------------------------------------------------------
// Split fp32 tensor into bf16 hi/lo planes.
// ---------------------------------------------------------------------------
__global__ __launch_bounds__(256)
void planes_k(const float* __restrict__ src, short* __restrict__ ph,
              short* __restrict__ pl)
{
    const int i = blockIdx.x * 256 + threadIdx.x;
    float4 f = ((const float4*)src)[i];
    float fa[4] = {f.x, f.y, f.z, f.w};
    s4v h4, l4;
#pragma unroll
    for (int j = 0; j < 4; j++) {
        unsigned short hb = f2bf(fa[j]);
        h4[j] = (short)hb;
        l4[j] = (short)f2bf(fa[j] - bf2f(hb));
    }
    ((s4v*)ph)[i] = h4;
    ((s4v*)pl)[i] = l4;
}

// ---------------------------------------------------------------------------
// QKV GEMM, tile 256x192 -> grid 16x16 = 256 blocks = EXACTLY 1/CU (100%
// fill).  8 waves, wave tile 64x96 (72 MFMA : 20 b128 reads = 3.6:1),
// double-buffered LDS (112 KB), ONE barrier per K-step (prefetch k+1 issued
// before compute of k).  3-term bf16 hi/lo.  Fused RMSNorm: heads A/C are
// wave-local; middle head B spans the wave pair -> epilogue cross-wave
// partial-sum exchange through (dead) staging LDS, 1 extra barrier.
// q pre-scaled by 0.125*log2(e).  Scatter to q/k hi/lo planes + sigma V^T.
// ---------------------------------------------------------------------------
__global__ __launch_bounds__(512, 2)
void gemm_qkv2(const short* __restrict__ Ah, const short* __restrict__ Al,
               const short* __restrict__ Bh, const short* __restrict__ Bl,
               short* __restrict__ Qhp, short* __restrict__ Qlp,
               short* __restrict__ Khp, short* __restrict__ Klp,
               short* __restrict__ Vp,
               const float* __restrict__ qw, const float* __restrict__ kw)
{
    extern __shared__ short L[];             // 57344 shorts = 112 KB
    short* sAh = L;                          // [2][8192]
    short* sAl = L + 16384;                  // [2][8192]
    short* sBh = L + 32768;                  // [2][6144]
    short* sBl = L + 45056;                  // [2][6144]

    const int t = threadIdx.x, w = t >> 6, lane = t & 63;
    const int col = lane & 15, quad = lane >> 4;
    const int wm = w >> 1;                   // 0..3 -> 64-row band
    const int wn = w & 1;                    // 0..1 -> 96-col half
    const int m0 = blockIdx.y * 256, n0 = blockIdx.x * 192;

    f4v acc[4][6];
#pragma unroll
    for (int i = 0; i < 4; i++)
#pragma unroll
        for (int j = 0; j < 6; j++) { f4v z = {0.f,0.f,0.f,0.f}; acc[i][j] = z; }

    // ---- staging: A 1024 chunks (2/thread), B 768 chunks (2/thread, t<384)
    // chunk c -> row c>>2, dst-chunk c&3, source k-chunk (c&3)^(row&3).
    const int ca0 = t, ca1 = t + 512;
    const int cb0 = t, cb1 = t + 384;
    const bool doB = t < 384;
    #define SRCOFF(c, base, rbase) ((size_t)((rbase) + ((c) >> 2))*1024 \
                                    + (((c) & 3) ^ (((c) >> 2) & 3))*8)

    auto stage = [&](int k0, int pp) {
        gl_lds16(Ah + SRCOFF(ca0, 0, m0) + k0, &sAh[pp*8192 + ca0*8]);
        gl_lds16(Ah + SRCOFF(ca1, 0, m0) + k0, &sAh[pp*8192 + ca1*8]);
        gl_lds16(Al + SRCOFF(ca0, 0, m0) + k0, &sAl[pp*8192 + ca0*8]);
        gl_lds16(Al + SRCOFF(ca1, 0, m0) + k0, &sAl[pp*8192 + ca1*8]);
        if (doB) {
            gl_lds16(Bh + SRCOFF(cb0, 0, n0) + k0, &sBh[pp*6144 + cb0*8]);
            gl_lds16(Bh + SRCOFF(cb1, 0, n0) + k0, &sBh[pp*6144 + cb1*8]);
            gl_lds16(Bl + SRCOFF(cb0, 0, n0) + k0, &sBl[pp*6144 + cb0*8]);
            gl_lds16(Bl + SRCOFF(cb1, 0, n0) + k0, &sBl[pp*6144 + cb1*8]);
        }
    };

    stage(0, 0);
    __syncthreads();

    for (int kt = 0; kt < 32; kt++) {
        const int pp = kt & 1;
        if (kt < 31) stage((kt + 1) * 32, pp ^ 1);

        const int swz = ((quad ^ (col & 3)) << 3);
        s8v bhf[6], blf[6];
#pragma unroll
        for (int j = 0; j < 6; j++) {
            const int boff = pp*6144 + (wn*96 + j*16 + col)*32 + swz;
            bhf[j] = *(const s8v*)&sBh[boff];
            blf[j] = *(const s8v*)&sBl[boff];
        }
#pragma unroll
        for (int i = 0; i < 4; i++) {
            const int aoff = pp*8192 + (wm*64 + i*16 + col)*32 + swz;
            s8v ah = *(const s8v*)&sAh[aoff];
            s8v al = *(const s8v*)&sAl[aoff];
#pragma unroll
            for (int j = 0; j < 6; j++) {
                acc[i][j] = mfma32(ah, bhf[j], acc[i][j]);
                acc[i][j] = mfma32(ah, blf[j], acc[i][j]);
                acc[i][j] = mfma32(al, bhf[j], acc[i][j]);
            }
        }
        __syncthreads();                 // drains prefetch; all reads of pp done
    }

    // ---- fused RMSNorm ----
    // full head F: wn=0 -> frags 0-3 (cols n0..n0+63); wn=1 -> frags 2-5
    // (cols n0+128..191).  boundary head B: cols n0+64..127, frags {4,5}@wn0
    // + {0,1}@wn1.
    const int whichF = (n0 + wn*128) >> 10;
    const int whichB = (n0 + 64) >> 10;
    const int j0  = 2*wn;                 // full-head first frag
    const int jb0 = 4 - 4*wn;             // boundary-head first frag

    if (whichF < 2) {
        const float* nw = (whichF == 0) ? qw : kw;
        const float sfac = (whichF == 0) ? (0.125f * L2E) : 1.0f;
        float wj[4];
#pragma unroll
        for (int j = 0; j < 4; j++) wj[j] = nw[j*16 + col] * sfac;
#pragma unroll
        for (int i = 0; i < 4; i++)
#pragma unroll
        for (int r = 0; r < 4; r++) {
            float s2 = acc[i][j0+0][r]*acc[i][j0+0][r]
                     + acc[i][j0+1][r]*acc[i][j0+1][r]
                     + acc[i][j0+2][r]*acc[i][j0+2][r]
                     + acc[i][j0+3][r]*acc[i][j0+3][r];
            s2 += __shfl_xor(s2, 1);
            s2 += __shfl_xor(s2, 2);
            s2 += __shfl_xor(s2, 4);
            s2 += __shfl_xor(s2, 8);
            const float scn = rsqrtf(s2*(1.0f/64.0f) + 1e-6f);
#pragma unroll
            for (int j = 0; j < 4; j++) acc[i][j0+j][r] *= scn*wj[j];
        }
    }

    // boundary head: partial sums + cross-wave exchange via dead staging LDS
    float pB[4][4];
    float* pb = (float*)L;                // [2][256] floats, reuse sAh region
    if (whichB < 2) {
#pragma unroll
        for (int i = 0; i < 4; i++)
#pragma unroll
        for (int r = 0; r < 4; r++) {
            float s2 = acc[i][jb0][r]*acc[i][jb0][r]
                     + acc[i][jb0+1][r]*acc[i][jb0+1][r];
            s2 += __shfl_xor(s2, 1);
            s2 += __shfl_xor(s2, 2);
            s2 += __shfl_xor(s2, 4);
            s2 += __shfl_xor(s2, 8);
            pB[i][r] = s2;
        }
        if (col == 0) {
#pragma unroll
            for (int i = 0; i < 4; i++)
#pragma unroll
            for (int r = 0; r < 4; r++)
                pb[wn*256 + wm*64 + i*16 + quad*4 + r] = pB[i][r];
        }
    }
    __syncthreads();
    if (whichB < 2) {
        const float* nw = (whichB == 0) ? qw : kw;
        const float sfac = (whichB == 0) ? (0.125f * L2E) : 1.0f;
        float wj[2];
#pragma unroll
        for (int j = 0; j < 2; j++) wj[j] = nw[(wn*2 + j)*16 + col] * sfac;
#pragma unroll
        for (int i = 0; i < 4; i++)
#pragma unroll
        for (int r = 0; r < 4; r++) {
            const float s2 = pB[i][r]
                + pb[(wn^1)*256 + wm*64 + i*16 + quad*4 + r];
            const float scn = rsqrtf(s2*(1.0f/64.0f) + 1e-6f);
            acc[i][jb0  ][r] *= scn*wj[0];
            acc[i][jb0+1][r] *= scn*wj[1];
        }
    }

    // ---- scatter ----
#pragma unroll
    for (int i = 0; i < 4; i++)
#pragma unroll
    for (int j = 0; j < 6; j++) {
        const int gcol = n0 + wn*96 + j*16 + col;
        const int which = gcol >> 10;           // wave-uniform per (wn,j)
        const int hh = (gcol >> 6) & 15;
        const int hd = gcol & 63;
        const int grow0 = m0 + wm*64 + i*16 + quad*4;
        const int b = grow0 >> 11, nn0 = grow0 & 2047;
        if (which == 2) {
            // V^T[b,h,d,n'] bf16, sigma key permutation in 64-block
            s4v hv;
#pragma unroll
            for (int r = 0; r < 4; r++) hv[r] = (short)f2bf(acc[i][j][r]);
            const int nswz = (nn0 & ~60) | ((nn0 & 12) << 2) | ((nn0 & 48) >> 2);
            *(s4v*)&Vp[((size_t)(b*16 + hh)*64 + hd)*2048 + nswz] = hv;
        } else {
            short* Hp = (which == 0) ? Qhp : Khp;
            short* Lp = (which == 0) ? Qlp : Klp;
            const size_t base = ((size_t)(b*16 + hh)*2048 + nn0)*64 + hd;
#pragma unroll
            for (int r = 0; r < 4; r++) {
                const float v = acc[i][j][r];
                const unsigned short hb = f2bf(v);
                union { float f; unsigned u; } rr; rr.f = v - bf2f(hb);
                Hp[base + (size_t)r*64] = (short)hb;
                Lp[base + (size_t)r*64] = (short)(rr.u >> 16);
            }
        }
    }
}

// ---------------------------------------------------------------------------
// Output-projection GEMM: 128x128 tiles, BK=32, 8 waves, dbuf LDS (64 KB),
// one barrier per K-step.  Grid 256 blocks (32x8 tiles) = 1/CU.
// ---------------------------------------------------------------------------
template<int MODE, int NT>
__global__ __launch_bounds__(512, 2)
void gemm2(const short* __restrict__ Ah, const short* __restrict__ Al,
           const short* __restrict__ Bh, const short* __restrict__ Bl,
           float* __restrict__ Cout)
{
    extern __shared__ short L[];            // 32768 shorts = 64 KB
    short* sAh = L;
    short* sAl = L + 8192;
    short* sBh = L + 16384;
    short* sBl = L + 24576;

    const int t = threadIdx.x, w = t >> 6, lane = t & 63;
    const int col = lane & 15, quad = lane >> 4;
    const int wm = w >> 1;
    const int wn = w & 1;

    const int srow = t >> 2;
    const int sko  = ((t & 3) ^ (srow & 3)) * 8;
    const int sdst = t * 8;

    int tid = blockIdx.x;
    int m0 = (tid & 31) * 128, n0 = (tid >> 5) * 128;
    const short* agh = Ah + (size_t)(m0 + srow)*1024 + sko;
    const short* agl = Al + (size_t)(m0 + srow)*1024 + sko;
    const short* bgh = Bh + (size_t)(n0 + srow)*1024 + sko;
    const short* bgl = Bl + (size_t)(n0 + srow)*1024 + sko;

    auto stage = [&](int k0, int pp) {
        gl_lds16(agh + k0, &sAh[pp*4096 + sdst]);
        gl_lds16(agl + k0, &sAl[pp*4096 + sdst]);
        gl_lds16(bgh + k0, &sBh[pp*4096 + sdst]);
        gl_lds16(bgl + k0, &sBl[pp*4096 + sdst]);
    };
    stage(0, 0);
    __syncthreads();

    f4v acc[2][4];
#pragma unroll
    for (int i = 0; i < 2; i++)
#pragma unroll
        for (int j = 0; j < 4; j++) { f4v z = {0.f,0.f,0.f,0.f}; acc[i][j] = z; }

    for (int kt = 0; kt < 32; kt++) {
        const int pp = kt & 1;
        if (kt < 31) stage((kt + 1) * 32, pp ^ 1);

        const int swz = ((quad ^ (col & 3)) << 3);
        s8v bhf[4], blf[4];
#pragma unroll
        for (int j = 0; j < 4; j++) {
            const int boff = pp*4096 + (wn*64 + j*16 + col)*32 + swz;
            bhf[j] = *(const s8v*)&sBh[boff];
            blf[j] = *(const s8v*)&sBl[boff];
        }
#pragma unroll
        for (int i = 0; i < 2; i++) {
            const int aoff = pp*4096 + (wm*32 + i*16 + col)*32 + swz;
            s8v ah = *(const s8v*)&sAh[aoff];
            s8v al = *(const s8v*)&sAl[aoff];
#pragma unroll
            for (int j = 0; j < 4; j++) {
                acc[i][j] = mfma32(ah, bhf[j], acc[i][j]);
                acc[i][j] = mfma32(ah, blf[j], acc[i][j]);
                acc[i][j] = mfma32(al, bhf[j], acc[i][j]);
            }
        }
        __syncthreads();
    }

#pragma unroll
    for (int i = 0; i < 2; i++)
#pragma unroll
    for (int j = 0; j < 4; j++) {
        const int gcol = n0 + wn*64 + j*16 + col;
#pragma unroll
        for (int r = 0; r < 4; r++) {
            const int grow = m0 + wm*32 + i*16 + quad*4 + r;
            Cout[(size_t)grow*1024 + gcol] = acc[i][j][r];
        }
    }
}

// ---------------------------------------------------------------------------
// rowscale[b,q] = 1 / max(max_k dot4(cm[b,:,q], cm[b,:,k]), 1e-6)
// ---------------------------------------------------------------------------
__global__ __launch_bounds__(256)
void rowscale_k(const float* __restrict__ cm, float* __restrict__ rs)
{
    __shared__ float cms[4][2048];
    const int b  = blockIdx.x >> 5;
    const int qt = blockIdx.x & 31;
    const float* base = cm + (size_t)b * 4 * 2048;
    for (int i = threadIdx.x; i < 2048; i += 256) {
        cms[0][i] = base[i];
        cms[1][i] = base[2048 + i];
        cms[2][i] = base[4096 + i];
        cms[3][i] = base[6144 + i];
    }
    __syncthreads();
    const int q    = qt * 64 + (threadIdx.x >> 2);
    const int part = threadIdx.x & 3;
    const float a0 = cms[0][q], a1 = cms[1][q], a2 = cms[2][q], a3 = cms[3][q];
    float mx = 0.f;
    for (int i = 0; i < 512; i++) {
        const int k = part + 4 * i;
        float d = a0*cms[0][k] + a1*cms[1][k] + a2*cms[2][k] + a3*cms[3][k];
        mx = fmaxf(mx, d);
    }
    mx = fmaxf(mx, __shfl_xor(mx, 1));
    mx = fmaxf(mx, __shfl_xor(mx, 2));
    if (part == 0) rs[b * 2048 + q] = 1.0f / fmaxf(mx, 1e-6f);
}

// ---------------------------------------------------------------------------
// Bias precompute, pre-scaled by 3*log2(e) (gate applied in attn):
//  Bias2[b][k>>2][q][k&3] = ((dot4*rsq - 0.5)*2 + 0.3*im) * 3*L2E
// ---------------------------------------------------------------------------
__global__ __launch_bounds__(256)
void bias_pre(const float* __restrict__ cm, const float* __restrict__ im,
              const float* __restrict__ rs, float* __restrict__ Bias2)
{
    const int bid = blockIdx.x;
    const int qq = bid & 15;
    const int kt = (bid >> 4) & 31;
    const int b  = bid >> 9;

    __shared__ float cmk[4][64];
    const int t = threadIdx.x;
    const int k0 = kt * 64;
    cmk[t >> 6][t & 63] = cm[(size_t)b*8192 + (t >> 6)*2048 + k0 + (t & 63)];
    __syncthreads();

    const int klane = t & 15;
    const int qrow  = t >> 4;
    const int kk = k0 + klane*4;
    const int kg = kk >> 2;
    float ck[4][4];
#pragma unroll
    for (int c = 0; c < 4; c++)
#pragma unroll
        for (int j = 0; j < 4; j++) ck[c][j] = cmk[c][klane*4 + j];

    const float* cmb = cm + (size_t)b * 8192;
    const float kS = 3.0f * L2E;
    for (int it = 0; it < 8; it++) {
        const int q = qq*128 + it*16 + qrow;
        float4 imv = *(const float4*)(im + ((size_t)b*2048 + q)*2048 + kk);
        const float rsq = rs[b*2048 + q];
        const float c0 = cmb[q], c1 = cmb[2048+q], c2 = cmb[4096+q], c3 = cmb[6144+q];
        float o[4];
        float iv[4] = {imv.x, imv.y, imv.z, imv.w};
#pragma unroll
        for (int j = 0; j < 4; j++) {
            float same = c0*ck[0][j] + c1*ck[1][j] + c2*ck[2][j] + c3*ck[3][j];
            o[j] = ((same*rsq - 0.5f)*2.0f + 0.3f*iv[j]) * kS;
        }
        *(float4*)(Bias2 + (((size_t)b*512 + kg)*2048 + q)*4) =
            make_float4(o[0], o[1], o[2], o[3]);
    }
}

// ---------------------------------------------------------------------------
// Flash attention, S^T orientation.  q-tile 128 (32 q/wave), 512 blocks,
// 2 blocks/CU.  K AND V staged by global_load_lds DMA (double-buffered,
// XOR source swizzle); V arrives sigma-permuted+pre-transposed so PV runs
// as 16x16x32 MFMA with conflict-free b128 LDS reads and zero shuffles.
// li accumulated by MFMA (ones-vector row-sum).  One barrier per tile.
// Softmax: NO-MAX (scores provably bounded |sr|<=17.2 by RMSNorm
// Cauchy-Schwarz + bias bound; exp2 range-safe in bf16).
// ---------------------------------------------------------------------------
__global__ __launch_bounds__(256, 2)
void attn_mfma(const short* __restrict__ Qhp, const short* __restrict__ Qlp,
               const short* __restrict__ Khg, const short* __restrict__ Klg,
               const short* __restrict__ VtG, const float* __restrict__ Bias2,
               const float* __restrict__ gate, short* __restrict__ Oh,
               short* __restrict__ Ol)
{
    const int bid = blockIdx.x;
    const int h  = bid & 15;
    const int qt = (bid >> 4) & 15;
    const int b  = bid >> 8;

    __shared__ __align__(16) short Kbuf[2][2][64*64];   // [pp][hi/lo][key][d] swz
    __shared__ __align__(16) short Vbuf[2][64*64];      // [pp][d][sigma-key swz]

    const int t    = threadIdx.x;
    const int w    = t >> 6;
    const int lane = t & 63;
    const int col  = lane & 15;
    const int quad = lane >> 4;

    const size_t headoff = ((size_t)(b*16 + h)) * 2048 * 64;
    const int qb = qt*128 + w*32;

    // ---- Q B-fragments (hi/lo) straight from planes (q pre-scaled) ----
    s8v qfh[2][2], qfl[2][2];
#pragma unroll
    for (int n = 0; n < 2; n++)
#pragma unroll
    for (int c = 0; c < 2; c++) {
        const size_t off = headoff + (size_t)(qb + n*16 + col)*64 + c*32 + quad*8;
        qfh[n][c] = *(const s8v*)(Qhp + off);
        qfl[n][c] = *(const s8v*)(Qlp + off);
    }

    const float g = fminf(fmaxf(gate[h], 0.f), 1.f);

    s8v ones8;
#pragma unroll
    for (int j = 0; j < 8; j++) ones8[j] = (short)0x3F80;   // bf16 1.0

    f4v liacc[2];
    f4v Oa[4][2];
    {
        f4v z = {0.f,0.f,0.f,0.f};
        liacc[0] = z; liacc[1] = z;
#pragma unroll
        for (int dt = 0; dt < 4; dt++)
#pragma unroll
            for (int n = 0; n < 2; n++) Oa[dt][n] = z;
    }

    // ---- staging bases ----
    const short* ksrc_h = Khg + headoff + (size_t)(w*8 + (lane>>3))*64
                          + ((lane&7) ^ (lane>>3))*8;
    const short* ksrc_l = Klg + headoff + (size_t)(w*8 + (lane>>3))*64
                          + ((lane&7) ^ (lane>>3))*8;
    // V^T rows: d = cc*32 + w*8 + (lane>>3); sigma-key-group XOR by d&7
    const short* vsrcT = VtG + headoff + (size_t)(w*8 + (lane>>3))*2048
                          + ((lane&7) ^ (lane>>3))*8;

    const float* bptr[2];
#pragma unroll
    for (int n = 0; n < 2; n++)
        bptr[n] = Bias2 + (((size_t)b*512 + quad)*2048 + qb + n*16 + col)*4;

    auto dma = [&](int kbase, int pp) {
#pragma unroll
        for (int j = 0; j < 2; j++) {
            gl_lds16(ksrc_h + (size_t)kbase*64 + j*2048, &Kbuf[pp][0][(j*4 + w)*512]);
            gl_lds16(ksrc_l + (size_t)kbase*64 + j*2048, &Kbuf[pp][1][(j*4 + w)*512]);
        }
#pragma unroll
        for (int cc = 0; cc < 2; cc++)
            gl_lds16(vsrcT + (size_t)(kbase + cc*65536), &Vbuf[pp][cc*2048 + w*512]);
    };

    float4 biasA[4][2], biasB[4][2];

    // ---- prologue: tile 0 ----
    dma(0, 0);
#pragma unroll
    for (int s = 0; s < 4; s++)
#pragma unroll
    for (int n = 0; n < 2; n++)
        biasA[s][n] = *(const float4*)(bptr[n] + (size_t)s*4*8192);
    __syncthreads();

    auto tile = [&](int kt, int pp, float4 (&BC)[4][2], float4 (&BN)[4][2]) {
        const int kbase = kt * 64;
        const bool pre = kt < 31;
        if (pre) {
            dma(kbase + 64, pp ^ 1);
#pragma unroll
            for (int s = 0; s < 4; s++)
#pragma unroll
            for (int n = 0; n < 2; n++)
                BN[s][n] = *(const float4*)(bptr[n] +
                    ((size_t)((kbase >> 2) + 16) + s*4)*8192);
        }

        // ---- S^T = K·Q^T (3-term hi/lo), scales pre-folded ----
        f4v S[4][2];
#pragma unroll
        for (int s = 0; s < 4; s++)
#pragma unroll
            for (int n = 0; n < 2; n++) { f4v z = {0.f,0.f,0.f,0.f}; S[s][n] = z; }
#pragma unroll
        for (int s = 0; s < 4; s++)
#pragma unroll
        for (int c = 0; c < 2; c++) {
            const int koff = (s*16 + col)*64 + (((c*4 + quad) ^ (col & 7)) << 3);
            s8v kh = *(const s8v*)&Kbuf[pp][0][koff];
            s8v kl = *(const s8v*)&Kbuf[pp][1][koff];
#pragma unroll
            for (int n = 0; n < 2; n++) {
                S[s][n] = mfma32(kh, qfh[n][c], S[s][n]);
                S[s][n] = mfma32(kh, qfl[n][c], S[s][n]);
                S[s][n] = mfma32(kl, qfh[n][c], S[s][n]);
            }
        }

        // ---- bias (1 FMA) + no-max softmax: p = exp2(S + g*bias) ----
        s8v ph8[2][2];
#pragma unroll
        for (int n = 0; n < 2; n++) {
            union { unsigned uu[4]; s8v v; } pk0, pk1;
#pragma unroll
            for (int s = 0; s < 4; s++) {
                const float bb[4] = {BC[s][n].x, BC[s][n].y, BC[s][n].z, BC[s][n].w};
                const float p0 = exp2g(fmaf(bb[0], g, S[s][n][0]));
                const float p1 = exp2g(fmaf(bb[1], g, S[s][n][1]));
                const float p2 = exp2g(fmaf(bb[2], g, S[s][n][2]));
                const float p3 = exp2g(fmaf(bb[3], g, S[s][n][3]));
                unsigned u01, u23;
                asm("v_cvt_pk_bf16_f32 %0, %1, %2" : "=v"(u01) : "v"(p0), "v"(p1));
                asm("v_cvt_pk_bf16_f32 %0, %1, %2" : "=v"(u23) : "v"(p2), "v"(p3));
                if (s < 2) { pk0.uu[s*2] = u01;     pk0.uu[s*2 + 1] = u23; }
                else       { pk1.uu[(s-2)*2] = u01; pk1.uu[(s-2)*2 + 1] = u23; }
            }
            ph8[n][0] = pk0.v;
            ph8[n][1] = pk1.v;
        }

        // ---- li row-sum by MFMA (rows of C identical; only [0] consumed) ----
#pragma unroll
        for (int n = 0; n < 2; n++)
#pragma unroll
        for (int m = 0; m < 2; m++)
            liacc[n] = mfma32(ones8, ph8[n][m], liacc[n]);

        // ---- O^T += V^T·P^T  (16x16x32, conflict-free b128 V reads) ----
#pragma unroll
        for (int dt = 0; dt < 4; dt++) {
            const int vrow = (dt*16 + col)*64;
            s8v v0 = *(const s8v*)&Vbuf[pp][vrow + ((((quad*2)    ) ^ (col & 7)) << 3)];
            s8v v1 = *(const s8v*)&Vbuf[pp][vrow + ((((quad*2) + 1) ^ (col & 7)) << 3)];
#pragma unroll
            for (int n = 0; n < 2; n++) {
                Oa[dt][n] = mfma32(v0, ph8[n][0], Oa[dt][n]);
                Oa[dt][n] = mfma32(v1, ph8[n][1], Oa[dt][n]);
            }
        }

        if (pre) __syncthreads();   // drains own DMA; all waves done with pp
    };

    for (int kt = 0; kt < 32; kt += 2) {
        tile(kt,     0, biasA, biasB);
        tile(kt + 1, 1, biasB, biasA);
    }

    // ---- epilogue: O^T -> bf16 hi/lo o-planes (B,N,D) ----
#pragma unroll
    for (int n = 0; n < 2; n++) {
        const float inv = 1.0f / liacc[n][0];
        const size_t row = (size_t)b*2048 + qb + n*16 + col;
#pragma unroll
        for (int dt = 0; dt < 4; dt++) {
            s4v hv, lv;
#pragma unroll
            for (int r = 0; r < 4; r++) {
                float y = Oa[dt][n][r] * inv;
                unsigned short hb = f2bf(y);
                hv[r] = (short)hb;
                union { float f; unsigned u; } rr; rr.f = y - bf2f(hb);
                lv[r] = (short)(rr.u >> 16);
            }
            const size_t o = row*1024 + h*64 + dt*16 + quad*4;
            *(s4v*)&Oh[o] = hv;
            *(s4v*)&Ol[o] = lv;
        }
    }
}

// ---------------------------------------------------------------------------
extern "C" void kernel_launch(void* const* d_in, const int* in_sizes, int n_in,
                              void* d_out, int out_size, void* d_ws, size_t ws_size,
                              hipStream_t stream)
{
    const float* x    = (const float*)d_in[0];
    const float* cm   = (const float*)d_in[1];
    const float* im   = (const float*)d_in[2];
    const float* Wqkv = (const float*)d_in[3];
    const float* Wout = (const float*)d_in[4];
    const float* qw   = (const float*)d_in[5];
    const float* kw   = (const float*)d_in[6];
    const float* gate = (const float*)d_in[7];
    float* out = (float*)d_out;

    // ---- workspace layout (bytes) ----
    char* ws = (char*)d_ws;
    short* qhp = (short*)(ws);                    // 8.39 MB each
    short* qlp = (short*)(ws +  8388608);
    short* khp = (short*)(ws + 16777216);
    short* klp = (short*)(ws + 25165824);
    short* vp  = (short*)(ws + 33554432);         // V^T[b,h,d,n'] bf16 (sigma)
    short* oh  = (short*)(ws + 41943040);
    short* ol  = (short*)(ws + 50331648);
    short* woh = (short*)(ws + 58720256);         // 2.10 MB each
    short* wol = (short*)(ws + 60817408);
    float* rsb = (float*)(ws + 62914560);         // 16 KB
    char*  U   = ws + 62930944;                   // union region
    short* xh  = (short*)(U);                     // 8.39 MB (dead after gemm0)
    short* xl  = (short*)(U +  8388608);
    short* wqh = (short*)(U + 16777216);          // 6.29 MB
    short* wql = (short*)(U + 23068672);
    float* bias2 = (float*)(U);                   // 33.55 MB (after gemm0)

    static bool lds_init = false;
    if (!lds_init) {
        hipFuncSetAttribute((const void*)&gemm_qkv2,
                            hipFuncAttributeMaxDynamicSharedMemorySize, 114688);
        hipFuncSetAttribute((const void*)&gemm2<1,1>,
                            hipFuncAttributeMaxDynamicSharedMemorySize, 65536);
        lds_init = true;
    }

    // 1) split inputs into bf16 hi/lo planes
    planes_k<<<4096, 256, 0, stream>>>(x,    xh,  xl);
    planes_k<<<3072, 256, 0, stream>>>(Wqkv, wqh, wql);
    planes_k<<<1024, 256, 0, stream>>>(Wout, woh, wol);
    // 2) qkv projection: 256x192 tiles, 16x16 grid = exactly 1 block/CU
    gemm_qkv2<<<dim3(16, 16), 512, 114688, stream>>>(xh, xl, wqh, wql,
        qhp, qlp, khp, klp, vp, qw, kw);
    // 3) bias precompute (overwrites x/wq plane region — dead after gemm0)
    rowscale_k<<<64, 256, 0, stream>>>(cm, rsb);
    bias_pre<<<1024, 256, 0, stream>>>(cm, im, rsb, bias2);
    // 4) flash attention -> bf16 o-planes  (512 blocks = 2/CU, q-tile 128)
    attn_mfma<<<512, 256, 0, stream>>>(qhp, qlp, khp, klp, vp, bias2, gate,
                                       oh, ol);
    // 5) output projection: 256 blocks (32x8 tiles of 128^2) -> fp32 out
    gemm2<1,1><<<256, 512, 65536, stream>>>(oh, ol, woh, wol, out);
}

// Round 7
// 340.257 us; speedup vs baseline: 2.3005x; 2.3005x over previous
//
#include <hip/hip_runtime.h>
#include <math.h>

// Problem constants: B=2, N=2048, D=1024, H=16, HD=64, C=4

typedef __attribute__((ext_vector_type(8))) short s8v;
typedef __attribute__((ext_vector_type(4))) short s4v;
typedef __attribute__((ext_vector_type(4))) float f4v;

#define L2E 1.44269504088896340736f

__device__ __forceinline__ unsigned short f2bf(float x) {
    union { float f; unsigned u; } v; v.f = x;
    unsigned r = v.u + 0x7FFF + ((v.u >> 16) & 1);
    return (unsigned short)(r >> 16);
}
__device__ __forceinline__ float bf2f(unsigned short h) {
    union { unsigned u; float f; } v; v.u = ((unsigned)h) << 16;
    return v.f;
}
__device__ __forceinline__ f4v mfma32(s8v a, s8v b, f4v c) {
    return __builtin_amdgcn_mfma_f32_16x16x32_bf16(a, b, c, 0, 0, 0);
}
__device__ __forceinline__ void gl_lds16(const void* g, void* l) {
    __builtin_amdgcn_global_load_lds(
        (const __attribute__((address_space(1))) unsigned*)g,
        (__attribute__((address_space(3))) unsigned*)l, 16, 0, 0);
}
// raw v_exp_f32: 1 instr, no OCML range-fixup wrapper
__device__ __forceinline__ float exp2g(float x) {
    float r; asm("v_exp_f32 %0, %1" : "=v"(r) : "v"(x)); return r;
}

// ---- RMSNorm helpers with COMPILE-TIME acc indices (rule #20: runtime
// indices into register arrays force the whole array to scratch). ----
template<int J0>
__device__ __forceinline__ void rms_full(f4v (&acc)[4][6], const float* nw,
                                         float sfac, int col)
{
    float wj[4];
#pragma unroll
    for (int j = 0; j < 4; j++) wj[j] = nw[j*16 + col] * sfac;
#pragma unroll
    for (int i = 0; i < 4; i++)
#pragma unroll
    for (int r = 0; r < 4; r++) {
        float s2 = acc[i][J0+0][r]*acc[i][J0+0][r]
                 + acc[i][J0+1][r]*acc[i][J0+1][r]
                 + acc[i][J0+2][r]*acc[i][J0+2][r]
                 + acc[i][J0+3][r]*acc[i][J0+3][r];
        s2 += __shfl_xor(s2, 1);
        s2 += __shfl_xor(s2, 2);
        s2 += __shfl_xor(s2, 4);
        s2 += __shfl_xor(s2, 8);
        const float scn = rsqrtf(s2*(1.0f/64.0f) + 1e-6f);
#pragma unroll
        for (int j = 0; j < 4; j++) acc[i][J0+j][r] *= scn*wj[j];
    }
}

template<int JB0>
__device__ __forceinline__ void rms_bpart(const f4v (&acc)[4][6],
                                          float (&pB)[4][4])
{
#pragma unroll
    for (int i = 0; i < 4; i++)
#pragma unroll
    for (int r = 0; r < 4; r++) {
        float s2 = acc[i][JB0  ][r]*acc[i][JB0  ][r]
                 + acc[i][JB0+1][r]*acc[i][JB0+1][r];
        s2 += __shfl_xor(s2, 1);
        s2 += __shfl_xor(s2, 2);
        s2 += __shfl_xor(s2, 4);
        s2 += __shfl_xor(s2, 8);
        pB[i][r] = s2;
    }
}

template<int JB0>
__device__ __forceinline__ void rms_bfin(f4v (&acc)[4][6],
                                         const float (&pB)[4][4],
                                         const float* pbOther,
                                         float wj0, float wj1,
                                         int wm, int quad)
{
#pragma unroll
    for (int i = 0; i < 4; i++)
#pragma unroll
    for (int r = 0; r < 4; r++) {
        const float s2 = pB[i][r] + pbOther[wm*64 + i*16 + quad*4 + r];
        const float scn = rsqrtf(s2*(1.0f/64.0f) + 1e-6f);
        acc[i][JB0  ][r] *= scn*wj0;
        acc[i][JB0+1][r] *= scn*wj1;
    }
}

// ---------------------------------------------------------------------------
// Split fp32 tensor into bf16 hi/lo planes.
// ---------------------------------------------------------------------------
__global__ __launch_bounds__(256)
void planes_k(const float* __restrict__ src, short* __restrict__ ph,
              short* __restrict__ pl)
{
    const int i = blockIdx.x * 256 + threadIdx.x;
    float4 f = ((const float4*)src)[i];
    float fa[4] = {f.x, f.y, f.z, f.w};
    s4v h4, l4;
#pragma unroll
    for (int j = 0; j < 4; j++) {
        unsigned short hb = f2bf(fa[j]);
        h4[j] = (short)hb;
        l4[j] = (short)f2bf(fa[j] - bf2f(hb));
    }
    ((s4v*)ph)[i] = h4;
    ((s4v*)pl)[i] = l4;
}

// ---------------------------------------------------------------------------
// QKV GEMM, tile 256x192 -> grid 16x16 = 256 blocks = EXACTLY 1/CU (100%
// fill).  8 waves, wave tile 64x96 (72 MFMA : 20 b128 reads = 3.6:1),
// double-buffered LDS (112 KB), ONE barrier per K-step (prefetch k+1 issued
// before compute of k).  3-term bf16 hi/lo.  Fused RMSNorm: heads A/C are
// wave-local (template<J0> -> static indices); middle head B spans the wave
// pair -> epilogue cross-wave partial-sum exchange through dead staging LDS.
// q pre-scaled by 0.125*log2(e).  Scatter to q/k hi/lo planes + sigma V^T.
// ---------------------------------------------------------------------------
__global__ __launch_bounds__(512, 2)
void gemm_qkv2(const short* __restrict__ Ah, const short* __restrict__ Al,
               const short* __restrict__ Bh, const short* __restrict__ Bl,
               short* __restrict__ Qhp, short* __restrict__ Qlp,
               short* __restrict__ Khp, short* __restrict__ Klp,
               short* __restrict__ Vp,
               const float* __restrict__ qw, const float* __restrict__ kw)
{
    extern __shared__ short L[];             // 57344 shorts = 112 KB
    short* sAh = L;                          // [2][8192]
    short* sAl = L + 16384;                  // [2][8192]
    short* sBh = L + 32768;                  // [2][6144]
    short* sBl = L + 45056;                  // [2][6144]

    const int t = threadIdx.x, w = t >> 6, lane = t & 63;
    const int col = lane & 15, quad = lane >> 4;
    const int wm = w >> 1;                   // 0..3 -> 64-row band
    const int wn = w & 1;                    // 0..1 -> 96-col half
    const int m0 = blockIdx.y * 256, n0 = blockIdx.x * 192;

    f4v acc[4][6];
#pragma unroll
    for (int i = 0; i < 4; i++)
#pragma unroll
        for (int j = 0; j < 6; j++) { f4v z = {0.f,0.f,0.f,0.f}; acc[i][j] = z; }

    // ---- staging: A 1024 chunks (2/thread), B 768 chunks (2/thread, t<384)
    // chunk c -> row c>>2, dst-chunk c&3, source k-chunk (c&3)^(row&3).
    const int ca0 = t, ca1 = t + 512;
    const int cb0 = t, cb1 = t + 384;
    const bool doB = t < 384;
    #define SRCOFF(c, rbase) ((size_t)((rbase) + ((c) >> 2))*1024 \
                              + (((c) & 3) ^ (((c) >> 2) & 3))*8)

    auto stage = [&](int k0, int pp) {
        gl_lds16(Ah + SRCOFF(ca0, m0) + k0, &sAh[pp*8192 + ca0*8]);
        gl_lds16(Ah + SRCOFF(ca1, m0) + k0, &sAh[pp*8192 + ca1*8]);
        gl_lds16(Al + SRCOFF(ca0, m0) + k0, &sAl[pp*8192 + ca0*8]);
        gl_lds16(Al + SRCOFF(ca1, m0) + k0, &sAl[pp*8192 + ca1*8]);
        if (doB) {
            gl_lds16(Bh + SRCOFF(cb0, n0) + k0, &sBh[pp*6144 + cb0*8]);
            gl_lds16(Bh + SRCOFF(cb1, n0) + k0, &sBh[pp*6144 + cb1*8]);
            gl_lds16(Bl + SRCOFF(cb0, n0) + k0, &sBl[pp*6144 + cb0*8]);
            gl_lds16(Bl + SRCOFF(cb1, n0) + k0, &sBl[pp*6144 + cb1*8]);
        }
    };

    stage(0, 0);
    __syncthreads();

    for (int kt = 0; kt < 32; kt++) {
        const int pp = kt & 1;
        if (kt < 31) stage((kt + 1) * 32, pp ^ 1);

        const int swz = ((quad ^ (col & 3)) << 3);
        s8v bhf[6], blf[6];
#pragma unroll
        for (int j = 0; j < 6; j++) {
            const int boff = pp*6144 + (wn*96 + j*16 + col)*32 + swz;
            bhf[j] = *(const s8v*)&sBh[boff];
            blf[j] = *(const s8v*)&sBl[boff];
        }
#pragma unroll
        for (int i = 0; i < 4; i++) {
            const int aoff = pp*8192 + (wm*64 + i*16 + col)*32 + swz;
            s8v ah = *(const s8v*)&sAh[aoff];
            s8v al = *(const s8v*)&sAl[aoff];
#pragma unroll
            for (int j = 0; j < 6; j++) {
                acc[i][j] = mfma32(ah, bhf[j], acc[i][j]);
                acc[i][j] = mfma32(ah, blf[j], acc[i][j]);
                acc[i][j] = mfma32(al, bhf[j], acc[i][j]);
            }
        }
        __syncthreads();                 // drains prefetch; all reads of pp done
    }

    // ---- fused RMSNorm (all acc indices compile-time via templates) ----
    // wn=0: full head = frags 0-3 (cols n0..63), boundary part = frags 4,5
    //       (hd 0..31 of head at n0+64).
    // wn=1: full head = frags 2-5 (cols n0+128..191), boundary part = frags
    //       0,1 (hd 32..63 of head at n0+64).
    const int whichF = (n0 + wn*128) >> 10;
    const int whichB = (n0 + 64) >> 10;
    float pB[4][4];
    float* pb = (float*)L;                // [2][256] floats, dead staging LDS

    if (wn == 0) {
        if (whichF < 2)
            rms_full<0>(acc, (whichF == 0) ? qw : kw,
                        (whichF == 0) ? (0.125f * L2E) : 1.0f, col);
        if (whichB < 2) {
            rms_bpart<4>(acc, pB);
            if (col == 0) {
#pragma unroll
                for (int i = 0; i < 4; i++)
#pragma unroll
                for (int r = 0; r < 4; r++)
                    pb[wm*64 + i*16 + quad*4 + r] = pB[i][r];
            }
        }
    } else {
        if (whichF < 2)
            rms_full<2>(acc, (whichF == 0) ? qw : kw,
                        (whichF == 0) ? (0.125f * L2E) : 1.0f, col);
        if (whichB < 2) {
            rms_bpart<0>(acc, pB);
            if (col == 0) {
#pragma unroll
                for (int i = 0; i < 4; i++)
#pragma unroll
                for (int r = 0; r < 4; r++)
                    pb[256 + wm*64 + i*16 + quad*4 + r] = pB[i][r];
            }
        }
    }
    __syncthreads();
    if (whichB < 2) {
        const float* nw = (whichB == 0) ? qw : kw;
        const float sfac = (whichB == 0) ? (0.125f * L2E) : 1.0f;
        if (wn == 0)
            rms_bfin<4>(acc, pB, pb + 256,
                        nw[col]*sfac, nw[16 + col]*sfac, wm, quad);
        else
            rms_bfin<0>(acc, pB, pb,
                        nw[32 + col]*sfac, nw[48 + col]*sfac, wm, quad);
    }

    // ---- scatter ----
#pragma unroll
    for (int i = 0; i < 4; i++)
#pragma unroll
    for (int j = 0; j < 6; j++) {
        const int gcol = n0 + wn*96 + j*16 + col;
        const int which = gcol >> 10;           // wave-uniform per (wn,j)
        const int hh = (gcol >> 6) & 15;
        const int hd = gcol & 63;
        const int grow0 = m0 + wm*64 + i*16 + quad*4;
        const int b = grow0 >> 11, nn0 = grow0 & 2047;
        if (which == 2) {
            // V^T[b,h,d,n'] bf16, sigma key permutation in 64-block
            s4v hv;
#pragma unroll
            for (int r = 0; r < 4; r++) hv[r] = (short)f2bf(acc[i][j][r]);
            const int nswz = (nn0 & ~60) | ((nn0 & 12) << 2) | ((nn0 & 48) >> 2);
            *(s4v*)&Vp[((size_t)(b*16 + hh)*64 + hd)*2048 + nswz] = hv;
        } else {
            short* Hp = (which == 0) ? Qhp : Khp;
            short* Lp = (which == 0) ? Qlp : Klp;
            const size_t base = ((size_t)(b*16 + hh)*2048 + nn0)*64 + hd;
#pragma unroll
            for (int r = 0; r < 4; r++) {
                const float v = acc[i][j][r];
                const unsigned short hb = f2bf(v);
                union { float f; unsigned u; } rr; rr.f = v - bf2f(hb);
                Hp[base + (size_t)r*64] = (short)hb;
                Lp[base + (size_t)r*64] = (short)(rr.u >> 16);
            }
        }
    }
}

// ---------------------------------------------------------------------------
// Output-projection GEMM: 128x128 tiles, BK=32, 8 waves, dbuf LDS (64 KB),
// one barrier per K-step.  Grid 256 blocks (32x8 tiles) = 1/CU.
// ---------------------------------------------------------------------------
__global__ __launch_bounds__(512, 2)
void gemm_out2(const short* __restrict__ Ah, const short* __restrict__ Al,
               const short* __restrict__ Bh, const short* __restrict__ Bl,
               float* __restrict__ Cout)
{
    extern __shared__ short L[];            // 32768 shorts = 64 KB
    short* sAh = L;
    short* sAl = L + 8192;
    short* sBh = L + 16384;
    short* sBl = L + 24576;

    const int t = threadIdx.x, w = t >> 6, lane = t & 63;
    const int col = lane & 15, quad = lane >> 4;
    const int wm = w >> 1;
    const int wn = w & 1;

    const int srow = t >> 2;
    const int sko  = ((t & 3) ^ (srow & 3)) * 8;
    const int sdst = t * 8;

    int tid = blockIdx.x;
    int m0 = (tid & 31) * 128, n0 = (tid >> 5) * 128;
    const short* agh = Ah + (size_t)(m0 + srow)*1024 + sko;
    const short* agl = Al + (size_t)(m0 + srow)*1024 + sko;
    const short* bgh = Bh + (size_t)(n0 + srow)*1024 + sko;
    const short* bgl = Bl + (size_t)(n0 + srow)*1024 + sko;

    auto stage = [&](int k0, int pp) {
        gl_lds16(agh + k0, &sAh[pp*4096 + sdst]);
        gl_lds16(agl + k0, &sAl[pp*4096 + sdst]);
        gl_lds16(bgh + k0, &sBh[pp*4096 + sdst]);
        gl_lds16(bgl + k0, &sBl[pp*4096 + sdst]);
    };
    stage(0, 0);
    __syncthreads();

    f4v acc[2][4];
#pragma unroll
    for (int i = 0; i < 2; i++)
#pragma unroll
        for (int j = 0; j < 4; j++) { f4v z = {0.f,0.f,0.f,0.f}; acc[i][j] = z; }

    for (int kt = 0; kt < 32; kt++) {
        const int pp = kt & 1;
        if (kt < 31) stage((kt + 1) * 32, pp ^ 1);

        const int swz = ((quad ^ (col & 3)) << 3);
        s8v bhf[4], blf[4];
#pragma unroll
        for (int j = 0; j < 4; j++) {
            const int boff = pp*4096 + (wn*64 + j*16 + col)*32 + swz;
            bhf[j] = *(const s8v*)&sBh[boff];
            blf[j] = *(const s8v*)&sBl[boff];
        }
#pragma unroll
        for (int i = 0; i < 2; i++) {
            const int aoff = pp*4096 + (wm*32 + i*16 + col)*32 + swz;
            s8v ah = *(const s8v*)&sAh[aoff];
            s8v al = *(const s8v*)&sAl[aoff];
#pragma unroll
            for (int j = 0; j < 4; j++) {
                acc[i][j] = mfma32(ah, bhf[j], acc[i][j]);
                acc[i][j] = mfma32(ah, blf[j], acc[i][j]);
                acc[i][j] = mfma32(al, bhf[j], acc[i][j]);
            }
        }
        __syncthreads();
    }

#pragma unroll
    for (int i = 0; i < 2; i++)
#pragma unroll
    for (int j = 0; j < 4; j++) {
        const int gcol = n0 + wn*64 + j*16 + col;
#pragma unroll
        for (int r = 0; r < 4; r++) {
            const int grow = m0 + wm*32 + i*16 + quad*4 + r;
            Cout[(size_t)grow*1024 + gcol] = acc[i][j][r];
        }
    }
}

// ---------------------------------------------------------------------------
// rowscale[b,q] = 1 / max(max_k dot4(cm[b,:,q], cm[b,:,k]), 1e-6)
// ---------------------------------------------------------------------------
__global__ __launch_bounds__(256)
void rowscale_k(const float* __restrict__ cm, float* __restrict__ rs)
{
    __shared__ float cms[4][2048];
    const int b  = blockIdx.x >> 5;
    const int qt = blockIdx.x & 31;
    const float* base = cm + (size_t)b * 4 * 2048;
    for (int i = threadIdx.x; i < 2048; i += 256) {
        cms[0][i] = base[i];
        cms[1][i] = base[2048 + i];
        cms[2][i] = base[4096 + i];
        cms[3][i] = base[6144 + i];
    }
    __syncthreads();
    const int q    = qt * 64 + (threadIdx.x >> 2);
    const int part = threadIdx.x & 3;
    const float a0 = cms[0][q], a1 = cms[1][q], a2 = cms[2][q], a3 = cms[3][q];
    float mx = 0.f;
    for (int i = 0; i < 512; i++) {
        const int k = part + 4 * i;
        float d = a0*cms[0][k] + a1*cms[1][k] + a2*cms[2][k] + a3*cms[3][k];
        mx = fmaxf(mx, d);
    }
    mx = fmaxf(mx, __shfl_xor(mx, 1));
    mx = fmaxf(mx, __shfl_xor(mx, 2));
    if (part == 0) rs[b * 2048 + q] = 1.0f / fmaxf(mx, 1e-6f);
}

// ---------------------------------------------------------------------------
// Bias precompute, pre-scaled by 3*log2(e) (gate applied in attn):
//  Bias2[b][k>>2][q][k&3] = ((dot4*rsq - 0.5)*2 + 0.3*im) * 3*L2E
// ---------------------------------------------------------------------------
__global__ __launch_bounds__(256)
void bias_pre(const float* __restrict__ cm, const float* __restrict__ im,
              const float* __restrict__ rs, float* __restrict__ Bias2)
{
    const int bid = blockIdx.x;
    const int qq = bid & 15;
    const int kt = (bid >> 4) & 31;
    const int b  = bid >> 9;

    __shared__ float cmk[4][64];
    const int t = threadIdx.x;
    const int k0 = kt * 64;
    cmk[t >> 6][t & 63] = cm[(size_t)b*8192 + (t >> 6)*2048 + k0 + (t & 63)];
    __syncthreads();

    const int klane = t & 15;
    const int qrow  = t >> 4;
    const int kk = k0 + klane*4;
    const int kg = kk >> 2;
    float ck[4][4];
#pragma unroll
    for (int c = 0; c < 4; c++)
#pragma unroll
        for (int j = 0; j < 4; j++) ck[c][j] = cmk[c][klane*4 + j];

    const float* cmb = cm + (size_t)b * 8192;
    const float kS = 3.0f * L2E;
    for (int it = 0; it < 8; it++) {
        const int q = qq*128 + it*16 + qrow;
        float4 imv = *(const float4*)(im + ((size_t)b*2048 + q)*2048 + kk);
        const float rsq = rs[b*2048 + q];
        const float c0 = cmb[q], c1 = cmb[2048+q], c2 = cmb[4096+q], c3 = cmb[6144+q];
        float o[4];
        float iv[4] = {imv.x, imv.y, imv.z, imv.w};
#pragma unroll
        for (int j = 0; j < 4; j++) {
            float same = c0*ck[0][j] + c1*ck[1][j] + c2*ck[2][j] + c3*ck[3][j];
            o[j] = ((same*rsq - 0.5f)*2.0f + 0.3f*iv[j]) * kS;
        }
        *(float4*)(Bias2 + (((size_t)b*512 + kg)*2048 + q)*4) =
            make_float4(o[0], o[1], o[2], o[3]);
    }
}

// ---------------------------------------------------------------------------
// Flash attention, S^T orientation.  q-tile 128 (32 q/wave), 512 blocks,
// 2 blocks/CU.  K AND V staged by global_load_lds DMA (double-buffered,
// XOR source swizzle); V arrives sigma-permuted+pre-transposed so PV runs
// as 16x16x32 MFMA with conflict-free b128 LDS reads and zero shuffles.
// li accumulated by MFMA (ones-vector row-sum).  One barrier per tile.
// Softmax: NO-MAX (scores provably bounded |sr|<=17.2 by RMSNorm
// Cauchy-Schwarz + bias bound; exp2 range-safe in bf16).
// ---------------------------------------------------------------------------
__global__ __launch_bounds__(256, 2)
void attn_mfma(const short* __restrict__ Qhp, const short* __restrict__ Qlp,
               const short* __restrict__ Khg, const short* __restrict__ Klg,
               const short* __restrict__ VtG, const float* __restrict__ Bias2,
               const float* __restrict__ gate, short* __restrict__ Oh,
               short* __restrict__ Ol)
{
    const int bid = blockIdx.x;
    const int h  = bid & 15;
    const int qt = (bid >> 4) & 15;
    const int b  = bid >> 8;

    __shared__ __align__(16) short Kbuf[2][2][64*64];   // [pp][hi/lo][key][d] swz
    __shared__ __align__(16) short Vbuf[2][64*64];      // [pp][d][sigma-key swz]

    const int t    = threadIdx.x;
    const int w    = t >> 6;
    const int lane = t & 63;
    const int col  = lane & 15;
    const int quad = lane >> 4;

    const size_t headoff = ((size_t)(b*16 + h)) * 2048 * 64;
    const int qb = qt*128 + w*32;

    // ---- Q B-fragments (hi/lo) straight from planes (q pre-scaled) ----
    s8v qfh[2][2], qfl[2][2];
#pragma unroll
    for (int n = 0; n < 2; n++)
#pragma unroll
    for (int c = 0; c < 2; c++) {
        const size_t off = headoff + (size_t)(qb + n*16 + col)*64 + c*32 + quad*8;
        qfh[n][c] = *(const s8v*)(Qhp + off);
        qfl[n][c] = *(const s8v*)(Qlp + off);
    }

    const float g = fminf(fmaxf(gate[h], 0.f), 1.f);

    s8v ones8;
#pragma unroll
    for (int j = 0; j < 8; j++) ones8[j] = (short)0x3F80;   // bf16 1.0

    f4v liacc[2];
    f4v Oa[4][2];
    {
        f4v z = {0.f,0.f,0.f,0.f};
        liacc[0] = z; liacc[1] = z;
#pragma unroll
        for (int dt = 0; dt < 4; dt++)
#pragma unroll
            for (int n = 0; n < 2; n++) Oa[dt][n] = z;
    }

    // ---- staging bases ----
    const short* ksrc_h = Khg + headoff + (size_t)(w*8 + (lane>>3))*64
                          + ((lane&7) ^ (lane>>3))*8;
    const short* ksrc_l = Klg + headoff + (size_t)(w*8 + (lane>>3))*64
                          + ((lane&7) ^ (lane>>3))*8;
    // V^T rows: d = cc*32 + w*8 + (lane>>3); sigma-key-group XOR by d&7
    const short* vsrcT = VtG + headoff + (size_t)(w*8 + (lane>>3))*2048
                          + ((lane&7) ^ (lane>>3))*8;

    const float* bptr[2];
#pragma unroll
    for (int n = 0; n < 2; n++)
        bptr[n] = Bias2 + (((size_t)b*512 + quad)*2048 + qb + n*16 + col)*4;

    auto dma = [&](int kbase, int pp) {
#pragma unroll
        for (int j = 0; j < 2; j++) {
            gl_lds16(ksrc_h + (size_t)kbase*64 + j*2048, &Kbuf[pp][0][(j*4 + w)*512]);
            gl_lds16(ksrc_l + (size_t)kbase*64 + j*2048, &Kbuf[pp][1][(j*4 + w)*512]);
        }
#pragma unroll
        for (int cc = 0; cc < 2; cc++)
            gl_lds16(vsrcT + (size_t)(kbase + cc*65536), &Vbuf[pp][cc*2048 + w*512]);
    };

    float4 biasA[4][2], biasB[4][2];

    // ---- prologue: tile 0 ----
    dma(0, 0);
#pragma unroll
    for (int s = 0; s < 4; s++)
#pragma unroll
    for (int n = 0; n < 2; n++)
        biasA[s][n] = *(const float4*)(bptr[n] + (size_t)s*4*8192);
    __syncthreads();

    auto tile = [&](int kt, int pp, float4 (&BC)[4][2], float4 (&BN)[4][2]) {
        const int kbase = kt * 64;
        const bool pre = kt < 31;
        if (pre) {
            dma(kbase + 64, pp ^ 1);
#pragma unroll
            for (int s = 0; s < 4; s++)
#pragma unroll
            for (int n = 0; n < 2; n++)
                BN[s][n] = *(const float4*)(bptr[n] +
                    ((size_t)((kbase >> 2) + 16) + s*4)*8192);
        }

        // ---- S^T = K·Q^T (3-term hi/lo), scales pre-folded ----
        f4v S[4][2];
#pragma unroll
        for (int s = 0; s < 4; s++)
#pragma unroll
            for (int n = 0; n < 2; n++) { f4v z = {0.f,0.f,0.f,0.f}; S[s][n] = z; }
#pragma unroll
        for (int s = 0; s < 4; s++)
#pragma unroll
        for (int c = 0; c < 2; c++) {
            const int koff = (s*16 + col)*64 + (((c*4 + quad) ^ (col & 7)) << 3);
            s8v kh = *(const s8v*)&Kbuf[pp][0][koff];
            s8v kl = *(const s8v*)&Kbuf[pp][1][koff];
#pragma unroll
            for (int n = 0; n < 2; n++) {
                S[s][n] = mfma32(kh, qfh[n][c], S[s][n]);
                S[s][n] = mfma32(kh, qfl[n][c], S[s][n]);
                S[s][n] = mfma32(kl, qfh[n][c], S[s][n]);
            }
        }

        // ---- bias (1 FMA) + no-max softmax: p = exp2(S + g*bias) ----
        s8v ph8[2][2];
#pragma unroll
        for (int n = 0; n < 2; n++) {
            union { unsigned uu[4]; s8v v; } pk0, pk1;
#pragma unroll
            for (int s = 0; s < 4; s++) {
                const float bb[4] = {BC[s][n].x, BC[s][n].y, BC[s][n].z, BC[s][n].w};
                const float p0 = exp2g(fmaf(bb[0], g, S[s][n][0]));
                const float p1 = exp2g(fmaf(bb[1], g, S[s][n][1]));
                const float p2 = exp2g(fmaf(bb[2], g, S[s][n][2]));
                const float p3 = exp2g(fmaf(bb[3], g, S[s][n][3]));
                unsigned u01, u23;
                asm("v_cvt_pk_bf16_f32 %0, %1, %2" : "=v"(u01) : "v"(p0), "v"(p1));
                asm("v_cvt_pk_bf16_f32 %0, %1, %2" : "=v"(u23) : "v"(p2), "v"(p3));
                if (s < 2) { pk0.uu[s*2] = u01;     pk0.uu[s*2 + 1] = u23; }
                else       { pk1.uu[(s-2)*2] = u01; pk1.uu[(s-2)*2 + 1] = u23; }
            }
            ph8[n][0] = pk0.v;
            ph8[n][1] = pk1.v;
        }

        // ---- li row-sum by MFMA (rows of C identical; only [0] consumed) ----
#pragma unroll
        for (int n = 0; n < 2; n++)
#pragma unroll
        for (int m = 0; m < 2; m++)
            liacc[n] = mfma32(ones8, ph8[n][m], liacc[n]);

        // ---- O^T += V^T·P^T  (16x16x32, conflict-free b128 V reads) ----
#pragma unroll
        for (int dt = 0; dt < 4; dt++) {
            const int vrow = (dt*16 + col)*64;
            s8v v0 = *(const s8v*)&Vbuf[pp][vrow + ((((quad*2)    ) ^ (col & 7)) << 3)];
            s8v v1 = *(const s8v*)&Vbuf[pp][vrow + ((((quad*2) + 1) ^ (col & 7)) << 3)];
#pragma unroll
            for (int n = 0; n < 2; n++) {
                Oa[dt][n] = mfma32(v0, ph8[n][0], Oa[dt][n]);
                Oa[dt][n] = mfma32(v1, ph8[n][1], Oa[dt][n]);
            }
        }

        if (pre) __syncthreads();   // drains own DMA; all waves done with pp
    };

    for (int kt = 0; kt < 32; kt += 2) {
        tile(kt,     0, biasA, biasB);
        tile(kt + 1, 1, biasB, biasA);
    }

    // ---- epilogue: O^T -> bf16 hi/lo o-planes (B,N,D) ----
#pragma unroll
    for (int n = 0; n < 2; n++) {
        const float inv = 1.0f / liacc[n][0];
        const size_t row = (size_t)b*2048 + qb + n*16 + col;
#pragma unroll
        for (int dt = 0; dt < 4; dt++) {
            s4v hv, lv;
#pragma unroll
            for (int r = 0; r < 4; r++) {
                float y = Oa[dt][n][r] * inv;
                unsigned short hb = f2bf(y);
                hv[r] = (short)hb;
                union { float f; unsigned u; } rr; rr.f = y - bf2f(hb);
                lv[r] = (short)(rr.u >> 16);
            }
            const size_t o = row*1024 + h*64 + dt*16 + quad*4;
            *(s4v*)&Oh[o] = hv;
            *(s4v*)&Ol[o] = lv;
        }
    }
}

// ---------------------------------------------------------------------------
extern "C" void kernel_launch(void* const* d_in, const int* in_sizes, int n_in,
                              void* d_out, int out_size, void* d_ws, size_t ws_size,
                              hipStream_t stream)
{
    const float* x    = (const float*)d_in[0];
    const float* cm   = (const float*)d_in[1];
    const float* im   = (const float*)d_in[2];
    const float* Wqkv = (const float*)d_in[3];
    const float* Wout = (const float*)d_in[4];
    const float* qw   = (const float*)d_in[5];
    const float* kw   = (const float*)d_in[6];
    const float* gate = (const float*)d_in[7];
    float* out = (float*)d_out;

    // ---- workspace layout (bytes) ----
    char* ws = (char*)d_ws;
    short* qhp = (short*)(ws);                    // 8.39 MB each
    short* qlp = (short*)(ws +  8388608);
    short* khp = (short*)(ws + 16777216);
    short* klp = (short*)(ws + 25165824);
    short* vp  = (short*)(ws + 33554432);         // V^T[b,h,d,n'] bf16 (sigma)
    short* oh  = (short*)(ws + 41943040);
    short* ol  = (short*)(ws + 50331648);
    short* woh = (short*)(ws + 58720256);         // 2.10 MB each
    short* wol = (short*)(ws + 60817408);
    float* rsb = (float*)(ws + 62914560);         // 16 KB
    char*  U   = ws + 62930944;                   // union region
    short* xh  = (short*)(U);                     // 8.39 MB (dead after gemm0)
    short* xl  = (short*)(U +  8388608);
    short* wqh = (short*)(U + 16777216);          // 6.29 MB
    short* wql = (short*)(U + 23068672);
    float* bias2 = (float*)(U);                   // 33.55 MB (after gemm0)

    static bool lds_init = false;
    if (!lds_init) {
        hipFuncSetAttribute((const void*)&gemm_qkv2,
                            hipFuncAttributeMaxDynamicSharedMemorySize, 114688);
        hipFuncSetAttribute((const void*)&gemm_out2,
                            hipFuncAttributeMaxDynamicSharedMemorySize, 65536);
        lds_init = true;
    }

    // 1) split inputs into bf16 hi/lo planes
    planes_k<<<4096, 256, 0, stream>>>(x,    xh,  xl);
    planes_k<<<3072, 256, 0, stream>>>(Wqkv, wqh, wql);
    planes_k<<<1024, 256, 0, stream>>>(Wout, woh, wol);
    // 2) qkv projection: 256x192 tiles, 16x16 grid = exactly 1 block/CU
    gemm_qkv2<<<dim3(16, 16), 512, 114688, stream>>>(xh, xl, wqh, wql,
        qhp, qlp, khp, klp, vp, qw, kw);
    // 3) bias precompute (overwrites x/wq plane region — dead after gemm0)
    rowscale_k<<<64, 256, 0, stream>>>(cm, rsb);
    bias_pre<<<1024, 256, 0, stream>>>(cm, im, rsb, bias2);
    // 4) flash attention -> bf16 o-planes  (512 blocks = 2/CU, q-tile 128)
    attn_mfma<<<512, 256, 0, stream>>>(qhp, qlp, khp, klp, vp, bias2, gate,
                                       oh, ol);
    // 5) output projection: 256 blocks (32x8 tiles of 128^2) -> fp32 out
    gemm_out2<<<256, 512, 65536, stream>>>(oh, ol, woh, wol, out);
}

// Round 8
// 335.246 us; speedup vs baseline: 2.3348x; 1.0149x over previous
//
#include <hip/hip_runtime.h>
#include <math.h>

// Problem constants: B=2, N=2048, D=1024, H=16, HD=64, C=4

typedef __attribute__((ext_vector_type(8))) short s8v;
typedef __attribute__((ext_vector_type(4))) short s4v;
typedef __attribute__((ext_vector_type(4))) float f4v;

#define L2E 1.44269504088896340736f

__device__ __forceinline__ unsigned short f2bf(float x) {
    union { float f; unsigned u; } v; v.f = x;
    unsigned r = v.u + 0x7FFF + ((v.u >> 16) & 1);
    return (unsigned short)(r >> 16);
}
__device__ __forceinline__ float bf2f(unsigned short h) {
    union { unsigned u; float f; } v; v.u = ((unsigned)h) << 16;
    return v.f;
}
__device__ __forceinline__ f4v mfma32(s8v a, s8v b, f4v c) {
    return __builtin_amdgcn_mfma_f32_16x16x32_bf16(a, b, c, 0, 0, 0);
}
__device__ __forceinline__ void gl_lds16(const void* g, void* l) {
    __builtin_amdgcn_global_load_lds(
        (const __attribute__((address_space(1))) unsigned*)g,
        (__attribute__((address_space(3))) unsigned*)l, 16, 0, 0);
}
// raw v_exp_f32: 1 instr, no OCML range-fixup wrapper
__device__ __forceinline__ float exp2g(float x) {
    float r; asm("v_exp_f32 %0, %1" : "=v"(r) : "v"(x)); return r;
}

// ---- RMSNorm helpers with COMPILE-TIME acc indices (rule #20: runtime
// indices into register arrays force the whole array to scratch). ----
template<int J0>
__device__ __forceinline__ void rms_full(f4v (&acc)[4][6], const float* nw,
                                         float sfac, int col)
{
    float wj[4];
#pragma unroll
    for (int j = 0; j < 4; j++) wj[j] = nw[j*16 + col] * sfac;
#pragma unroll
    for (int i = 0; i < 4; i++)
#pragma unroll
    for (int r = 0; r < 4; r++) {
        float s2 = acc[i][J0+0][r]*acc[i][J0+0][r]
                 + acc[i][J0+1][r]*acc[i][J0+1][r]
                 + acc[i][J0+2][r]*acc[i][J0+2][r]
                 + acc[i][J0+3][r]*acc[i][J0+3][r];
        s2 += __shfl_xor(s2, 1);
        s2 += __shfl_xor(s2, 2);
        s2 += __shfl_xor(s2, 4);
        s2 += __shfl_xor(s2, 8);
        const float scn = rsqrtf(s2*(1.0f/64.0f) + 1e-6f);
#pragma unroll
        for (int j = 0; j < 4; j++) acc[i][J0+j][r] *= scn*wj[j];
    }
}

template<int JB0>
__device__ __forceinline__ void rms_bpart(const f4v (&acc)[4][6],
                                          float (&pB)[4][4])
{
#pragma unroll
    for (int i = 0; i < 4; i++)
#pragma unroll
    for (int r = 0; r < 4; r++) {
        float s2 = acc[i][JB0  ][r]*acc[i][JB0  ][r]
                 + acc[i][JB0+1][r]*acc[i][JB0+1][r];
        s2 += __shfl_xor(s2, 1);
        s2 += __shfl_xor(s2, 2);
        s2 += __shfl_xor(s2, 4);
        s2 += __shfl_xor(s2, 8);
        pB[i][r] = s2;
    }
}

template<int JB0>
__device__ __forceinline__ void rms_bfin(f4v (&acc)[4][6],
                                         const float (&pB)[4][4],
                                         const float* pbOther,
                                         float wj0, float wj1,
                                         int wm, int quad)
{
#pragma unroll
    for (int i = 0; i < 4; i++)
#pragma unroll
    for (int r = 0; r < 4; r++) {
        const float s2 = pB[i][r] + pbOther[wm*64 + i*16 + quad*4 + r];
        const float scn = rsqrtf(s2*(1.0f/64.0f) + 1e-6f);
        acc[i][JB0  ][r] *= scn*wj0;
        acc[i][JB0+1][r] *= scn*wj1;
    }
}

// ---------------------------------------------------------------------------
// Split fp32 tensor into bf16 hi/lo planes.
// ---------------------------------------------------------------------------
__global__ __launch_bounds__(256)
void planes_k(const float* __restrict__ src, short* __restrict__ ph,
              short* __restrict__ pl)
{
    const int i = blockIdx.x * 256 + threadIdx.x;
    float4 f = ((const float4*)src)[i];
    float fa[4] = {f.x, f.y, f.z, f.w};
    s4v h4, l4;
#pragma unroll
    for (int j = 0; j < 4; j++) {
        unsigned short hb = f2bf(fa[j]);
        h4[j] = (short)hb;
        l4[j] = (short)f2bf(fa[j] - bf2f(hb));
    }
    ((s4v*)ph)[i] = h4;
    ((s4v*)pl)[i] = l4;
}

// ---------------------------------------------------------------------------
// QKV GEMM, tile 256x192 -> grid 16x16 = 256 blocks = EXACTLY 1/CU (100%
// fill).  8 waves, wave tile 64x96 (72 MFMA : 20 b128 reads = 3.6:1),
// double-buffered LDS (112 KB), ONE barrier per K-step (prefetch k+1 issued
// before compute of k).  3-term bf16 hi/lo.  Fused RMSNorm: heads A/C are
// wave-local (template<J0> -> static indices); middle head B spans the wave
// pair -> epilogue cross-wave partial-sum exchange through dead staging LDS.
// q pre-scaled by 0.125*log2(e).  Scatter to q/k hi/lo planes + sigma V^T.
// ---------------------------------------------------------------------------
__global__ __launch_bounds__(512, 2)
void gemm_qkv2(const short* __restrict__ Ah, const short* __restrict__ Al,
               const short* __restrict__ Bh, const short* __restrict__ Bl,
               short* __restrict__ Qhp, short* __restrict__ Qlp,
               short* __restrict__ Khp, short* __restrict__ Klp,
               short* __restrict__ Vp,
               const float* __restrict__ qw, const float* __restrict__ kw)
{
    extern __shared__ short L[];             // 57344 shorts = 112 KB
    short* sAh = L;                          // [2][8192]
    short* sAl = L + 16384;                  // [2][8192]
    short* sBh = L + 32768;                  // [2][6144]
    short* sBl = L + 45056;                  // [2][6144]

    const int t = threadIdx.x, w = t >> 6, lane = t & 63;
    const int col = lane & 15, quad = lane >> 4;
    const int wm = w >> 1;                   // 0..3 -> 64-row band
    const int wn = w & 1;                    // 0..1 -> 96-col half
    const int m0 = blockIdx.y * 256, n0 = blockIdx.x * 192;

    f4v acc[4][6];
#pragma unroll
    for (int i = 0; i < 4; i++)
#pragma unroll
        for (int j = 0; j < 6; j++) { f4v z = {0.f,0.f,0.f,0.f}; acc[i][j] = z; }

    // ---- staging: A 1024 chunks (2/thread), B 768 chunks (2/thread, t<384)
    // chunk c -> row c>>2, dst-chunk c&3, source k-chunk (c&3)^(row&3).
    const int ca0 = t, ca1 = t + 512;
    const int cb0 = t, cb1 = t + 384;
    const bool doB = t < 384;
    #define SRCOFF(c, rbase) ((size_t)((rbase) + ((c) >> 2))*1024 \
                              + (((c) & 3) ^ (((c) >> 2) & 3))*8)

    auto stage = [&](int k0, int pp) {
        gl_lds16(Ah + SRCOFF(ca0, m0) + k0, &sAh[pp*8192 + ca0*8]);
        gl_lds16(Ah + SRCOFF(ca1, m0) + k0, &sAh[pp*8192 + ca1*8]);
        gl_lds16(Al + SRCOFF(ca0, m0) + k0, &sAl[pp*8192 + ca0*8]);
        gl_lds16(Al + SRCOFF(ca1, m0) + k0, &sAl[pp*8192 + ca1*8]);
        if (doB) {
            gl_lds16(Bh + SRCOFF(cb0, n0) + k0, &sBh[pp*6144 + cb0*8]);
            gl_lds16(Bh + SRCOFF(cb1, n0) + k0, &sBh[pp*6144 + cb1*8]);
            gl_lds16(Bl + SRCOFF(cb0, n0) + k0, &sBl[pp*6144 + cb0*8]);
            gl_lds16(Bl + SRCOFF(cb1, n0) + k0, &sBl[pp*6144 + cb1*8]);
        }
    };

    stage(0, 0);
    __syncthreads();

    for (int kt = 0; kt < 32; kt++) {
        const int pp = kt & 1;
        if (kt < 31) stage((kt + 1) * 32, pp ^ 1);

        const int swz = ((quad ^ (col & 3)) << 3);
        s8v bhf[6], blf[6];
#pragma unroll
        for (int j = 0; j < 6; j++) {
            const int boff = pp*6144 + (wn*96 + j*16 + col)*32 + swz;
            bhf[j] = *(const s8v*)&sBh[boff];
            blf[j] = *(const s8v*)&sBl[boff];
        }
#pragma unroll
        for (int i = 0; i < 4; i++) {
            const int aoff = pp*8192 + (wm*64 + i*16 + col)*32 + swz;
            s8v ah = *(const s8v*)&sAh[aoff];
            s8v al = *(const s8v*)&sAl[aoff];
#pragma unroll
            for (int j = 0; j < 6; j++) {
                acc[i][j] = mfma32(ah, bhf[j], acc[i][j]);
                acc[i][j] = mfma32(ah, blf[j], acc[i][j]);
                acc[i][j] = mfma32(al, bhf[j], acc[i][j]);
            }
        }
        __syncthreads();                 // drains prefetch; all reads of pp done
    }

    // ---- fused RMSNorm (all acc indices compile-time via templates) ----
    const int whichF = (n0 + wn*128) >> 10;
    const int whichB = (n0 + 64) >> 10;
    float pB[4][4];
    float* pb = (float*)L;                // [2][256] floats, dead staging LDS

    if (wn == 0) {
        if (whichF < 2)
            rms_full<0>(acc, (whichF == 0) ? qw : kw,
                        (whichF == 0) ? (0.125f * L2E) : 1.0f, col);
        if (whichB < 2) {
            rms_bpart<4>(acc, pB);
            if (col == 0) {
#pragma unroll
                for (int i = 0; i < 4; i++)
#pragma unroll
                for (int r = 0; r < 4; r++)
                    pb[wm*64 + i*16 + quad*4 + r] = pB[i][r];
            }
        }
    } else {
        if (whichF < 2)
            rms_full<2>(acc, (whichF == 0) ? qw : kw,
                        (whichF == 0) ? (0.125f * L2E) : 1.0f, col);
        if (whichB < 2) {
            rms_bpart<0>(acc, pB);
            if (col == 0) {
#pragma unroll
                for (int i = 0; i < 4; i++)
#pragma unroll
                for (int r = 0; r < 4; r++)
                    pb[256 + wm*64 + i*16 + quad*4 + r] = pB[i][r];
            }
        }
    }
    __syncthreads();
    if (whichB < 2) {
        const float* nw = (whichB == 0) ? qw : kw;
        const float sfac = (whichB == 0) ? (0.125f * L2E) : 1.0f;
        if (wn == 0)
            rms_bfin<4>(acc, pB, pb + 256,
                        nw[col]*sfac, nw[16 + col]*sfac, wm, quad);
        else
            rms_bfin<0>(acc, pB, pb,
                        nw[32 + col]*sfac, nw[48 + col]*sfac, wm, quad);
    }

    // ---- scatter ----
#pragma unroll
    for (int i = 0; i < 4; i++)
#pragma unroll
    for (int j = 0; j < 6; j++) {
        const int gcol = n0 + wn*96 + j*16 + col;
        const int which = gcol >> 10;           // wave-uniform per (wn,j)
        const int hh = (gcol >> 6) & 15;
        const int hd = gcol & 63;
        const int grow0 = m0 + wm*64 + i*16 + quad*4;
        const int b = grow0 >> 11, nn0 = grow0 & 2047;
        if (which == 2) {
            // V^T[b,h,d,n'] bf16, sigma key permutation in 64-block
            s4v hv;
#pragma unroll
            for (int r = 0; r < 4; r++) hv[r] = (short)f2bf(acc[i][j][r]);
            const int nswz = (nn0 & ~60) | ((nn0 & 12) << 2) | ((nn0 & 48) >> 2);
            *(s4v*)&Vp[((size_t)(b*16 + hh)*64 + hd)*2048 + nswz] = hv;
        } else {
            short* Hp = (which == 0) ? Qhp : Khp;
            short* Lp = (which == 0) ? Qlp : Klp;
            const size_t base = ((size_t)(b*16 + hh)*2048 + nn0)*64 + hd;
#pragma unroll
            for (int r = 0; r < 4; r++) {
                const float v = acc[i][j][r];
                const unsigned short hb = f2bf(v);
                union { float f; unsigned u; } rr; rr.f = v - bf2f(hb);
                Hp[base + (size_t)r*64] = (short)hb;
                Lp[base + (size_t)r*64] = (short)(rr.u >> 16);
            }
        }
    }
}

// ---------------------------------------------------------------------------
// Output-projection GEMM: 128x128 tiles, BK=32, 8 waves, dbuf LDS (64 KB),
// one barrier per K-step.  Grid 256 blocks (32x8 tiles) = 1/CU.
// ---------------------------------------------------------------------------
__global__ __launch_bounds__(512, 2)
void gemm_out2(const short* __restrict__ Ah, const short* __restrict__ Al,
               const short* __restrict__ Bh, const short* __restrict__ Bl,
               float* __restrict__ Cout)
{
    extern __shared__ short L[];            // 32768 shorts = 64 KB
    short* sAh = L;
    short* sAl = L + 8192;
    short* sBh = L + 16384;
    short* sBl = L + 24576;

    const int t = threadIdx.x, w = t >> 6, lane = t & 63;
    const int col = lane & 15, quad = lane >> 4;
    const int wm = w >> 1;
    const int wn = w & 1;

    const int srow = t >> 2;
    const int sko  = ((t & 3) ^ (srow & 3)) * 8;
    const int sdst = t * 8;

    int tid = blockIdx.x;
    int m0 = (tid & 31) * 128, n0 = (tid >> 5) * 128;
    const short* agh = Ah + (size_t)(m0 + srow)*1024 + sko;
    const short* agl = Al + (size_t)(m0 + srow)*1024 + sko;
    const short* bgh = Bh + (size_t)(n0 + srow)*1024 + sko;
    const short* bgl = Bl + (size_t)(n0 + srow)*1024 + sko;

    auto stage = [&](int k0, int pp) {
        gl_lds16(agh + k0, &sAh[pp*4096 + sdst]);
        gl_lds16(agl + k0, &sAl[pp*4096 + sdst]);
        gl_lds16(bgh + k0, &sBh[pp*4096 + sdst]);
        gl_lds16(bgl + k0, &sBl[pp*4096 + sdst]);
    };
    stage(0, 0);
    __syncthreads();

    f4v acc[2][4];
#pragma unroll
    for (int i = 0; i < 2; i++)
#pragma unroll
        for (int j = 0; j < 4; j++) { f4v z = {0.f,0.f,0.f,0.f}; acc[i][j] = z; }

    for (int kt = 0; kt < 32; kt++) {
        const int pp = kt & 1;
        if (kt < 31) stage((kt + 1) * 32, pp ^ 1);

        const int swz = ((quad ^ (col & 3)) << 3);
        s8v bhf[4], blf[4];
#pragma unroll
        for (int j = 0; j < 4; j++) {
            const int boff = pp*4096 + (wn*64 + j*16 + col)*32 + swz;
            bhf[j] = *(const s8v*)&sBh[boff];
            blf[j] = *(const s8v*)&sBl[boff];
        }
#pragma unroll
        for (int i = 0; i < 2; i++) {
            const int aoff = pp*4096 + (wm*32 + i*16 + col)*32 + swz;
            s8v ah = *(const s8v*)&sAh[aoff];
            s8v al = *(const s8v*)&sAl[aoff];
#pragma unroll
            for (int j = 0; j < 4; j++) {
                acc[i][j] = mfma32(ah, bhf[j], acc[i][j]);
                acc[i][j] = mfma32(ah, blf[j], acc[i][j]);
                acc[i][j] = mfma32(al, bhf[j], acc[i][j]);
            }
        }
        __syncthreads();
    }

#pragma unroll
    for (int i = 0; i < 2; i++)
#pragma unroll
    for (int j = 0; j < 4; j++) {
        const int gcol = n0 + wn*64 + j*16 + col;
#pragma unroll
        for (int r = 0; r < 4; r++) {
            const int grow = m0 + wm*32 + i*16 + quad*4 + r;
            Cout[(size_t)grow*1024 + gcol] = acc[i][j][r];
        }
    }
}

// ---------------------------------------------------------------------------
// rowscale[b,q] = 1 / max(max_k dot4(cm[b,:,q], cm[b,:,k]), 1e-6)
// ---------------------------------------------------------------------------
__global__ __launch_bounds__(256)
void rowscale_k(const float* __restrict__ cm, float* __restrict__ rs)
{
    __shared__ float cms[4][2048];
    const int b  = blockIdx.x >> 5;
    const int qt = blockIdx.x & 31;
    const float* base = cm + (size_t)b * 4 * 2048;
    for (int i = threadIdx.x; i < 2048; i += 256) {
        cms[0][i] = base[i];
        cms[1][i] = base[2048 + i];
        cms[2][i] = base[4096 + i];
        cms[3][i] = base[6144 + i];
    }
    __syncthreads();
    const int q    = qt * 64 + (threadIdx.x >> 2);
    const int part = threadIdx.x & 3;
    const float a0 = cms[0][q], a1 = cms[1][q], a2 = cms[2][q], a3 = cms[3][q];
    float mx = 0.f;
    for (int i = 0; i < 512; i++) {
        const int k = part + 4 * i;
        float d = a0*cms[0][k] + a1*cms[1][k] + a2*cms[2][k] + a3*cms[3][k];
        mx = fmaxf(mx, d);
    }
    mx = fmaxf(mx, __shfl_xor(mx, 1));
    mx = fmaxf(mx, __shfl_xor(mx, 2));
    if (part == 0) rs[b * 2048 + q] = 1.0f / fmaxf(mx, 1e-6f);
}

// ---------------------------------------------------------------------------
// Bias precompute, pre-scaled by 3*log2(e) (gate applied in attn):
//  Bias2[b][k>>2][q][k&3] = ((dot4*rsq - 0.5)*2 + 0.3*im) * 3*L2E
// ---------------------------------------------------------------------------
__global__ __launch_bounds__(256)
void bias_pre(const float* __restrict__ cm, const float* __restrict__ im,
              const float* __restrict__ rs, float* __restrict__ Bias2)
{
    const int bid = blockIdx.x;
    const int qq = bid & 15;
    const int kt = (bid >> 4) & 31;
    const int b  = bid >> 9;

    __shared__ float cmk[4][64];
    const int t = threadIdx.x;
    const int k0 = kt * 64;
    cmk[t >> 6][t & 63] = cm[(size_t)b*8192 + (t >> 6)*2048 + k0 + (t & 63)];
    __syncthreads();

    const int klane = t & 15;
    const int qrow  = t >> 4;
    const int kk = k0 + klane*4;
    const int kg = kk >> 2;
    float ck[4][4];
#pragma unroll
    for (int c = 0; c < 4; c++)
#pragma unroll
        for (int j = 0; j < 4; j++) ck[c][j] = cmk[c][klane*4 + j];

    const float* cmb = cm + (size_t)b * 8192;
    const float kS = 3.0f * L2E;
    for (int it = 0; it < 8; it++) {
        const int q = qq*128 + it*16 + qrow;
        float4 imv = *(const float4*)(im + ((size_t)b*2048 + q)*2048 + kk);
        const float rsq = rs[b*2048 + q];
        const float c0 = cmb[q], c1 = cmb[2048+q], c2 = cmb[4096+q], c3 = cmb[6144+q];
        float o[4];
        float iv[4] = {imv.x, imv.y, imv.z, imv.w};
#pragma unroll
        for (int j = 0; j < 4; j++) {
            float same = c0*ck[0][j] + c1*ck[1][j] + c2*ck[2][j] + c3*ck[3][j];
            o[j] = ((same*rsq - 0.5f)*2.0f + 0.3f*iv[j]) * kS;
        }
        *(float4*)(Bias2 + (((size_t)b*512 + kg)*2048 + q)*4) =
            make_float4(o[0], o[1], o[2], o[3]);
    }
}

// ---------------------------------------------------------------------------
// Flash attention, S^T orientation.  q-tile 128 (32 q/wave), 512 blocks,
// 2 blocks/CU.  K AND V staged by global_load_lds DMA into a 3-BUFFER RING
// (72 KB dynamic LDS) with COUNTED vmcnt waits (T3/T4): prefetch runs 2
// tiles ahead; per tile `s_waitcnt vmcnt(14)` drains exactly dma(kt) while
// keeping bias(kt)+dma(kt+1) in flight, then raw s_barrier (no vmcnt(0)
// drain).  Issue order per tile: wait, barrier, bias(kt+1) loads [8],
// dma(kt+2) [6], compute.  WAR safe: barrier at tile kt ensures all waves
// finished tile kt-1's reads of buf[(kt-1)%3] before dma(kt+2) writes it.
// V sigma-permuted+pre-transposed (16x16x32 PV, conflict-free b128 reads);
// li by MFMA ones-row-sum; NO-MAX softmax (|sr|<=17.2 bound).
// ---------------------------------------------------------------------------
__global__ __launch_bounds__(256, 2)
void attn_mfma(const short* __restrict__ Qhp, const short* __restrict__ Qlp,
               const short* __restrict__ Khg, const short* __restrict__ Klg,
               const short* __restrict__ VtG, const float* __restrict__ Bias2,
               const float* __restrict__ gate, short* __restrict__ Oh,
               short* __restrict__ Ol)
{
    extern __shared__ short SL[];   // 73728 B: K ring [3][2][4096] + V ring [3][4096]
    short* Kb = SL;                 // pp*8192 + plane*4096 + off
    short* Vb = SL + 24576;         // pp*4096 + off

    const int bid = blockIdx.x;
    const int h  = bid & 15;
    const int qt = (bid >> 4) & 15;
    const int b  = bid >> 8;

    const int t    = threadIdx.x;
    const int w    = t >> 6;
    const int lane = t & 63;
    const int col  = lane & 15;
    const int quad = lane >> 4;

    const size_t headoff = ((size_t)(b*16 + h)) * 2048 * 64;
    const int qb = qt*128 + w*32;

    // ---- Q B-fragments (hi/lo) straight from planes (q pre-scaled) ----
    s8v qfh[2][2], qfl[2][2];
#pragma unroll
    for (int n = 0; n < 2; n++)
#pragma unroll
    for (int c = 0; c < 2; c++) {
        const size_t off = headoff + (size_t)(qb + n*16 + col)*64 + c*32 + quad*8;
        qfh[n][c] = *(const s8v*)(Qhp + off);
        qfl[n][c] = *(const s8v*)(Qlp + off);
    }

    const float g = fminf(fmaxf(gate[h], 0.f), 1.f);

    s8v ones8;
#pragma unroll
    for (int j = 0; j < 8; j++) ones8[j] = (short)0x3F80;   // bf16 1.0

    f4v liacc[2];
    f4v Oa[4][2];
    {
        f4v z = {0.f,0.f,0.f,0.f};
        liacc[0] = z; liacc[1] = z;
#pragma unroll
        for (int dt = 0; dt < 4; dt++)
#pragma unroll
            for (int n = 0; n < 2; n++) Oa[dt][n] = z;
    }

    // ---- staging bases ----
    const short* ksrc_h = Khg + headoff + (size_t)(w*8 + (lane>>3))*64
                          + ((lane&7) ^ (lane>>3))*8;
    const short* ksrc_l = Klg + headoff + (size_t)(w*8 + (lane>>3))*64
                          + ((lane&7) ^ (lane>>3))*8;
    // V^T rows: d = cc*32 + w*8 + (lane>>3); sigma-key-group XOR by d&7
    const short* vsrcT = VtG + headoff + (size_t)(w*8 + (lane>>3))*2048
                          + ((lane&7) ^ (lane>>3))*8;

    const float* bptr[2];
#pragma unroll
    for (int n = 0; n < 2; n++)
        bptr[n] = Bias2 + (((size_t)b*512 + quad)*2048 + qb + n*16 + col)*4;

    auto dma = [&](int kbase, int pp) {    // 6 loads/thread
#pragma unroll
        for (int j = 0; j < 2; j++) {
            gl_lds16(ksrc_h + (size_t)kbase*64 + j*2048,
                     &Kb[pp*8192 + (j*4 + w)*512]);
            gl_lds16(ksrc_l + (size_t)kbase*64 + j*2048,
                     &Kb[pp*8192 + 4096 + (j*4 + w)*512]);
        }
#pragma unroll
        for (int cc = 0; cc < 2; cc++)
            gl_lds16(vsrcT + (size_t)(kbase + cc*65536),
                     &Vb[pp*4096 + cc*2048 + w*512]);
    };

    float4 biasA[4][2], biasB[4][2];

    // ---- prologue: issue tiles 0 and 1; bias for tile 0 (8 loads) ----
    dma(0, 0);
    dma(64, 1);
#pragma unroll
    for (int s = 0; s < 4; s++)
#pragma unroll
    for (int n = 0; n < 2; n++)
        biasA[s][n] = *(const float4*)(bptr[n] + (size_t)s*4*8192);

    auto tile = [&](int kt, float4 (&BC)[4][2], float4 (&BN)[4][2]) {
        const int pp = kt % 3;
        const int kbase = kt * 64;
        // counted wait: drain dma(kt), keep bias(kt)[8]+dma(kt+1)[6] in flight
        if (kt < 31) asm volatile("s_waitcnt vmcnt(14)" ::: "memory");
        else         asm volatile("s_waitcnt vmcnt(8)"  ::: "memory");
        __builtin_amdgcn_s_barrier();
        if (kt < 31) {
            // bias prefetch for kt+1 (8 loads; issued BEFORE dma(kt+2))
#pragma unroll
            for (int s = 0; s < 4; s++)
#pragma unroll
            for (int n = 0; n < 2; n++)
                BN[s][n] = *(const float4*)(bptr[n] +
                    ((size_t)((kbase >> 2) + 16) + s*4)*8192);
        }
        if (kt < 30) dma((kt + 2) * 64, (kt + 2) % 3);

        // ---- S^T = K·Q^T (3-term hi/lo), scales pre-folded ----
        f4v S[4][2];
#pragma unroll
        for (int s = 0; s < 4; s++)
#pragma unroll
            for (int n = 0; n < 2; n++) { f4v z = {0.f,0.f,0.f,0.f}; S[s][n] = z; }
#pragma unroll
        for (int s = 0; s < 4; s++)
#pragma unroll
        for (int c = 0; c < 2; c++) {
            const int koff = (s*16 + col)*64 + (((c*4 + quad) ^ (col & 7)) << 3);
            s8v kh = *(const s8v*)&Kb[pp*8192 + koff];
            s8v kl = *(const s8v*)&Kb[pp*8192 + 4096 + koff];
#pragma unroll
            for (int n = 0; n < 2; n++) {
                S[s][n] = mfma32(kh, qfh[n][c], S[s][n]);
                S[s][n] = mfma32(kh, qfl[n][c], S[s][n]);
                S[s][n] = mfma32(kl, qfh[n][c], S[s][n]);
            }
        }

        // ---- bias (1 FMA) + no-max softmax: p = exp2(S + g*bias) ----
        s8v ph8[2][2];
#pragma unroll
        for (int n = 0; n < 2; n++) {
            union { unsigned uu[4]; s8v v; } pk0, pk1;
#pragma unroll
            for (int s = 0; s < 4; s++) {
                const float bb[4] = {BC[s][n].x, BC[s][n].y, BC[s][n].z, BC[s][n].w};
                const float p0 = exp2g(fmaf(bb[0], g, S[s][n][0]));
                const float p1 = exp2g(fmaf(bb[1], g, S[s][n][1]));
                const float p2 = exp2g(fmaf(bb[2], g, S[s][n][2]));
                const float p3 = exp2g(fmaf(bb[3], g, S[s][n][3]));
                unsigned u01, u23;
                asm("v_cvt_pk_bf16_f32 %0, %1, %2" : "=v"(u01) : "v"(p0), "v"(p1));
                asm("v_cvt_pk_bf16_f32 %0, %1, %2" : "=v"(u23) : "v"(p2), "v"(p3));
                if (s < 2) { pk0.uu[s*2] = u01;     pk0.uu[s*2 + 1] = u23; }
                else       { pk1.uu[(s-2)*2] = u01; pk1.uu[(s-2)*2 + 1] = u23; }
            }
            ph8[n][0] = pk0.v;
            ph8[n][1] = pk1.v;
        }

        // ---- li row-sum by MFMA (rows of C identical; only [0] consumed) ----
#pragma unroll
        for (int n = 0; n < 2; n++)
#pragma unroll
        for (int m = 0; m < 2; m++)
            liacc[n] = mfma32(ones8, ph8[n][m], liacc[n]);

        // ---- O^T += V^T·P^T  (16x16x32, conflict-free b128 V reads) ----
#pragma unroll
        for (int dt = 0; dt < 4; dt++) {
            const int vrow = pp*4096 + (dt*16 + col)*64;
            s8v v0 = *(const s8v*)&Vb[vrow + ((((quad*2)    ) ^ (col & 7)) << 3)];
            s8v v1 = *(const s8v*)&Vb[vrow + ((((quad*2) + 1) ^ (col & 7)) << 3)];
#pragma unroll
            for (int n = 0; n < 2; n++) {
                Oa[dt][n] = mfma32(v0, ph8[n][0], Oa[dt][n]);
                Oa[dt][n] = mfma32(v1, ph8[n][1], Oa[dt][n]);
            }
        }
    };

    for (int kt = 0; kt < 32; kt += 2) {
        tile(kt,     biasA, biasB);
        tile(kt + 1, biasB, biasA);
    }

    // ---- epilogue: O^T -> bf16 hi/lo o-planes (B,N,D) ----
#pragma unroll
    for (int n = 0; n < 2; n++) {
        const float inv = 1.0f / liacc[n][0];
        const size_t row = (size_t)b*2048 + qb + n*16 + col;
#pragma unroll
        for (int dt = 0; dt < 4; dt++) {
            s4v hv, lv;
#pragma unroll
            for (int r = 0; r < 4; r++) {
                float y = Oa[dt][n][r] * inv;
                unsigned short hb = f2bf(y);
                hv[r] = (short)hb;
                union { float f; unsigned u; } rr; rr.f = y - bf2f(hb);
                lv[r] = (short)(rr.u >> 16);
            }
            const size_t o = row*1024 + h*64 + dt*16 + quad*4;
            *(s4v*)&Oh[o] = hv;
            *(s4v*)&Ol[o] = lv;
        }
    }
}

// ---------------------------------------------------------------------------
extern "C" void kernel_launch(void* const* d_in, const int* in_sizes, int n_in,
                              void* d_out, int out_size, void* d_ws, size_t ws_size,
                              hipStream_t stream)
{
    const float* x    = (const float*)d_in[0];
    const float* cm   = (const float*)d_in[1];
    const float* im   = (const float*)d_in[2];
    const float* Wqkv = (const float*)d_in[3];
    const float* Wout = (const float*)d_in[4];
    const float* qw   = (const float*)d_in[5];
    const float* kw   = (const float*)d_in[6];
    const float* gate = (const float*)d_in[7];
    float* out = (float*)d_out;

    // ---- workspace layout (bytes) ----
    char* ws = (char*)d_ws;
    short* qhp = (short*)(ws);                    // 8.39 MB each
    short* qlp = (short*)(ws +  8388608);
    short* khp = (short*)(ws + 16777216);
    short* klp = (short*)(ws + 25165824);
    short* vp  = (short*)(ws + 33554432);         // V^T[b,h,d,n'] bf16 (sigma)
    short* oh  = (short*)(ws + 41943040);
    short* ol  = (short*)(ws + 50331648);
    short* woh = (short*)(ws + 58720256);         // 2.10 MB each
    short* wol = (short*)(ws + 60817408);
    float* rsb = (float*)(ws + 62914560);         // 16 KB
    char*  U   = ws + 62930944;                   // union region
    short* xh  = (short*)(U);                     // 8.39 MB (dead after gemm0)
    short* xl  = (short*)(U +  8388608);
    short* wqh = (short*)(U + 16777216);          // 6.29 MB
    short* wql = (short*)(U + 23068672);
    float* bias2 = (float*)(U);                   // 33.55 MB (after gemm0)

    static bool lds_init = false;
    if (!lds_init) {
        hipFuncSetAttribute((const void*)&gemm_qkv2,
                            hipFuncAttributeMaxDynamicSharedMemorySize, 114688);
        hipFuncSetAttribute((const void*)&gemm_out2,
                            hipFuncAttributeMaxDynamicSharedMemorySize, 65536);
        hipFuncSetAttribute((const void*)&attn_mfma,
                            hipFuncAttributeMaxDynamicSharedMemorySize, 73728);
        lds_init = true;
    }

    // 1) split inputs into bf16 hi/lo planes
    planes_k<<<4096, 256, 0, stream>>>(x,    xh,  xl);
    planes_k<<<3072, 256, 0, stream>>>(Wqkv, wqh, wql);
    planes_k<<<1024, 256, 0, stream>>>(Wout, woh, wol);
    // 2) qkv projection: 256x192 tiles, 16x16 grid = exactly 1 block/CU
    gemm_qkv2<<<dim3(16, 16), 512, 114688, stream>>>(xh, xl, wqh, wql,
        qhp, qlp, khp, klp, vp, qw, kw);
    // 3) bias precompute (overwrites x/wq plane region — dead after gemm0)
    rowscale_k<<<64, 256, 0, stream>>>(cm, rsb);
    bias_pre<<<1024, 256, 0, stream>>>(cm, im, rsb, bias2);
    // 4) flash attention -> bf16 o-planes  (512 blocks = 2/CU, ring LDS)
    attn_mfma<<<512, 256, 73728, stream>>>(qhp, qlp, khp, klp, vp, bias2, gate,
                                           oh, ol);
    // 5) output projection: 256 blocks (32x8 tiles of 128^2) -> fp32 out
    gemm_out2<<<256, 512, 65536, stream>>>(oh, ol, woh, wol, out);
}

// Round 10
// 305.471 us; speedup vs baseline: 2.5624x; 1.0975x over previous
//
#include <hip/hip_runtime.h>
#include <math.h>

// Problem constants: B=2, N=2048, D=1024, H=16, HD=64, C=4

typedef __attribute__((ext_vector_type(8))) short s8v;
typedef __attribute__((ext_vector_type(4))) short s4v;
typedef __attribute__((ext_vector_type(4))) float f4v;
typedef __attribute__((ext_vector_type(8))) _Float16 h8v;
typedef __attribute__((ext_vector_type(2))) __fp16 fp16x2;

#define L2E 1.44269504088896340736f

__device__ __forceinline__ unsigned short f2bf(float x) {
    union { float f; unsigned u; } v; v.f = x;
    unsigned r = v.u + 0x7FFF + ((v.u >> 16) & 1);
    return (unsigned short)(r >> 16);
}
__device__ __forceinline__ float bf2f(unsigned short h) {
    union { unsigned u; float f; } v; v.u = ((unsigned)h) << 16;
    return v.f;
}
__device__ __forceinline__ short f2h(float x) {
    union { _Float16 h; short s; } cv; cv.h = (_Float16)x; return cv.s;
}
__device__ __forceinline__ f4v mfma32(s8v a, s8v b, f4v c) {
    return __builtin_amdgcn_mfma_f32_16x16x32_bf16(a, b, c, 0, 0, 0);
}
__device__ __forceinline__ f4v mfma16f(h8v a, h8v b, f4v c) {
    return __builtin_amdgcn_mfma_f32_16x16x32_f16(a, b, c, 0, 0, 0);
}
__device__ __forceinline__ void gl_lds16(const void* g, void* l) {
    __builtin_amdgcn_global_load_lds(
        (const __attribute__((address_space(1))) unsigned*)g,
        (__attribute__((address_space(3))) unsigned*)l, 16, 0, 0);
}
// raw v_exp_f32: 1 instr, no OCML range-fixup wrapper
__device__ __forceinline__ float exp2g(float x) {
    float r; asm("v_exp_f32 %0, %1" : "=v"(r) : "v"(x)); return r;
}

// ---- RMSNorm helpers with COMPILE-TIME acc indices (rule #20). ----
template<int J0>
__device__ __forceinline__ void rms_full(f4v (&acc)[4][6], const float* nw,
                                         float sfac, int col)
{
    float wj[4];
#pragma unroll
    for (int j = 0; j < 4; j++) wj[j] = nw[j*16 + col] * sfac;
#pragma unroll
    for (int i = 0; i < 4; i++)
#pragma unroll
    for (int r = 0; r < 4; r++) {
        float s2 = acc[i][J0+0][r]*acc[i][J0+0][r]
                 + acc[i][J0+1][r]*acc[i][J0+1][r]
                 + acc[i][J0+2][r]*acc[i][J0+2][r]
                 + acc[i][J0+3][r]*acc[i][J0+3][r];
        s2 += __shfl_xor(s2, 1);
        s2 += __shfl_xor(s2, 2);
        s2 += __shfl_xor(s2, 4);
        s2 += __shfl_xor(s2, 8);
        const float scn = rsqrtf(s2*(1.0f/64.0f) + 1e-6f);
#pragma unroll
        for (int j = 0; j < 4; j++) acc[i][J0+j][r] *= scn*wj[j];
    }
}

template<int JB0>
__device__ __forceinline__ void rms_bpart(const f4v (&acc)[4][6],
                                          float (&pB)[4][4])
{
#pragma unroll
    for (int i = 0; i < 4; i++)
#pragma unroll
    for (int r = 0; r < 4; r++) {
        float s2 = acc[i][JB0  ][r]*acc[i][JB0  ][r]
                 + acc[i][JB0+1][r]*acc[i][JB0+1][r];
        s2 += __shfl_xor(s2, 1);
        s2 += __shfl_xor(s2, 2);
        s2 += __shfl_xor(s2, 4);
        s2 += __shfl_xor(s2, 8);
        pB[i][r] = s2;
    }
}

template<int JB0>
__device__ __forceinline__ void rms_bfin(f4v (&acc)[4][6],
                                         const float (&pB)[4][4],
                                         const float* pbOther,
                                         float wj0, float wj1,
                                         int wm, int quad)
{
#pragma unroll
    for (int i = 0; i < 4; i++)
#pragma unroll
    for (int r = 0; r < 4; r++) {
        const float s2 = pB[i][r] + pbOther[wm*64 + i*16 + quad*4 + r];
        const float scn = rsqrtf(s2*(1.0f/64.0f) + 1e-6f);
        acc[i][JB0  ][r] *= scn*wj0;
        acc[i][JB0+1][r] *= scn*wj1;
    }
}

// ---------------------------------------------------------------------------
// Split fp32 tensor into bf16 hi/lo planes.
// ---------------------------------------------------------------------------
__global__ __launch_bounds__(256)
void planes_k(const float* __restrict__ src, short* __restrict__ ph,
              short* __restrict__ pl)
{
    const int i = blockIdx.x * 256 + threadIdx.x;
    float4 f = ((const float4*)src)[i];
    float fa[4] = {f.x, f.y, f.z, f.w};
    s4v h4, l4;
#pragma unroll
    for (int j = 0; j < 4; j++) {
        unsigned short hb = f2bf(fa[j]);
        h4[j] = (short)hb;
        l4[j] = (short)f2bf(fa[j] - bf2f(hb));
    }
    ((s4v*)ph)[i] = h4;
    ((s4v*)pl)[i] = l4;
}

// ---------------------------------------------------------------------------
// QKV GEMM, tile 256x192 -> grid 16x16 = 256 blocks = EXACTLY 1/CU.
// 8 waves, wave tile 64x96, double-buffered LDS (112 KB), ONE barrier per
// K-step.  3-term bf16 hi/lo.  Fused RMSNorm (template<J0> static indices;
// boundary head via cross-wave LDS exchange).  q pre-scaled by
// 0.125*log2(e).  OUTPUT: q/k as SINGLE fp16 planes; V^T fp16 with sigma
// key permutation (attn QK^T runs one fp16 MFMA term).
// ---------------------------------------------------------------------------
__global__ __launch_bounds__(512, 2)
void gemm_qkv2(const short* __restrict__ Ah, const short* __restrict__ Al,
               const short* __restrict__ Bh, const short* __restrict__ Bl,
               short* __restrict__ Qp, short* __restrict__ Kp,
               short* __restrict__ Vp,
               const float* __restrict__ qw, const float* __restrict__ kw)
{
    extern __shared__ short L[];             // 57344 shorts = 112 KB
    short* sAh = L;                          // [2][8192]
    short* sAl = L + 16384;                  // [2][8192]
    short* sBh = L + 32768;                  // [2][6144]
    short* sBl = L + 45056;                  // [2][6144]

    const int t = threadIdx.x, w = t >> 6, lane = t & 63;
    const int col = lane & 15, quad = lane >> 4;
    const int wm = w >> 1;                   // 0..3 -> 64-row band
    const int wn = w & 1;                    // 0..1 -> 96-col half
    const int m0 = blockIdx.y * 256, n0 = blockIdx.x * 192;

    f4v acc[4][6];
#pragma unroll
    for (int i = 0; i < 4; i++)
#pragma unroll
        for (int j = 0; j < 6; j++) { f4v z = {0.f,0.f,0.f,0.f}; acc[i][j] = z; }

    const int ca0 = t, ca1 = t + 512;
    const int cb0 = t, cb1 = t + 384;
    const bool doB = t < 384;
    #define SRCOFF(c, rbase) ((size_t)((rbase) + ((c) >> 2))*1024 \
                              + (((c) & 3) ^ (((c) >> 2) & 3))*8)

    auto stage = [&](int k0, int pp) {
        gl_lds16(Ah + SRCOFF(ca0, m0) + k0, &sAh[pp*8192 + ca0*8]);
        gl_lds16(Ah + SRCOFF(ca1, m0) + k0, &sAh[pp*8192 + ca1*8]);
        gl_lds16(Al + SRCOFF(ca0, m0) + k0, &sAl[pp*8192 + ca0*8]);
        gl_lds16(Al + SRCOFF(ca1, m0) + k0, &sAl[pp*8192 + ca1*8]);
        if (doB) {
            gl_lds16(Bh + SRCOFF(cb0, n0) + k0, &sBh[pp*6144 + cb0*8]);
            gl_lds16(Bh + SRCOFF(cb1, n0) + k0, &sBh[pp*6144 + cb1*8]);
            gl_lds16(Bl + SRCOFF(cb0, n0) + k0, &sBl[pp*6144 + cb0*8]);
            gl_lds16(Bl + SRCOFF(cb1, n0) + k0, &sBl[pp*6144 + cb1*8]);
        }
    };

    stage(0, 0);
    __syncthreads();

    for (int kt = 0; kt < 32; kt++) {
        const int pp = kt & 1;
        if (kt < 31) stage((kt + 1) * 32, pp ^ 1);

        const int swz = ((quad ^ (col & 3)) << 3);
        s8v bhf[6], blf[6];
#pragma unroll
        for (int j = 0; j < 6; j++) {
            const int boff = pp*6144 + (wn*96 + j*16 + col)*32 + swz;
            bhf[j] = *(const s8v*)&sBh[boff];
            blf[j] = *(const s8v*)&sBl[boff];
        }
#pragma unroll
        for (int i = 0; i < 4; i++) {
            const int aoff = pp*8192 + (wm*64 + i*16 + col)*32 + swz;
            s8v ah = *(const s8v*)&sAh[aoff];
            s8v al = *(const s8v*)&sAl[aoff];
#pragma unroll
            for (int j = 0; j < 6; j++) {
                acc[i][j] = mfma32(ah, bhf[j], acc[i][j]);
                acc[i][j] = mfma32(ah, blf[j], acc[i][j]);
                acc[i][j] = mfma32(al, bhf[j], acc[i][j]);
            }
        }
        __syncthreads();                 // drains prefetch; all reads of pp done
    }

    // ---- fused RMSNorm (all acc indices compile-time via templates) ----
    const int whichF = (n0 + wn*128) >> 10;
    const int whichB = (n0 + 64) >> 10;
    float pB[4][4];
    float* pb = (float*)L;                // [2][256] floats, dead staging LDS

    if (wn == 0) {
        if (whichF < 2)
            rms_full<0>(acc, (whichF == 0) ? qw : kw,
                        (whichF == 0) ? (0.125f * L2E) : 1.0f, col);
        if (whichB < 2) {
            rms_bpart<4>(acc, pB);
            if (col == 0) {
#pragma unroll
                for (int i = 0; i < 4; i++)
#pragma unroll
                for (int r = 0; r < 4; r++)
                    pb[wm*64 + i*16 + quad*4 + r] = pB[i][r];
            }
        }
    } else {
        if (whichF < 2)
            rms_full<2>(acc, (whichF == 0) ? qw : kw,
                        (whichF == 0) ? (0.125f * L2E) : 1.0f, col);
        if (whichB < 2) {
            rms_bpart<0>(acc, pB);
            if (col == 0) {
#pragma unroll
                for (int i = 0; i < 4; i++)
#pragma unroll
                for (int r = 0; r < 4; r++)
                    pb[256 + wm*64 + i*16 + quad*4 + r] = pB[i][r];
            }
        }
    }
    __syncthreads();
    if (whichB < 2) {
        const float* nw = (whichB == 0) ? qw : kw;
        const float sfac = (whichB == 0) ? (0.125f * L2E) : 1.0f;
        if (wn == 0)
            rms_bfin<4>(acc, pB, pb + 256,
                        nw[col]*sfac, nw[16 + col]*sfac, wm, quad);
        else
            rms_bfin<0>(acc, pB, pb,
                        nw[32 + col]*sfac, nw[48 + col]*sfac, wm, quad);
    }

    // ---- scatter: q/k single fp16 plane; V^T fp16 sigma-permuted ----
#pragma unroll
    for (int i = 0; i < 4; i++)
#pragma unroll
    for (int j = 0; j < 6; j++) {
        const int gcol = n0 + wn*96 + j*16 + col;
        const int which = gcol >> 10;           // wave-uniform per (wn,j)
        const int hh = (gcol >> 6) & 15;
        const int hd = gcol & 63;
        const int grow0 = m0 + wm*64 + i*16 + quad*4;
        const int b = grow0 >> 11, nn0 = grow0 & 2047;
        if (which == 2) {
            s4v hv;
#pragma unroll
            for (int r = 0; r < 4; r++) hv[r] = f2h(acc[i][j][r]);
            const int nswz = (nn0 & ~60) | ((nn0 & 12) << 2) | ((nn0 & 48) >> 2);
            *(s4v*)&Vp[((size_t)(b*16 + hh)*64 + hd)*2048 + nswz] = hv;
        } else {
            short* Pp = (which == 0) ? Qp : Kp;
            const size_t base = ((size_t)(b*16 + hh)*2048 + nn0)*64 + hd;
#pragma unroll
            for (int r = 0; r < 4; r++)
                Pp[base + (size_t)r*64] = f2h(acc[i][j][r]);
        }
    }
}

// ---------------------------------------------------------------------------
// Output-projection GEMM: 128x128 tiles, BK=32, 8 waves, dbuf LDS (64 KB),
// one barrier per K-step.  Grid 256 blocks (32x8 tiles) = 1/CU.
// ---------------------------------------------------------------------------
__global__ __launch_bounds__(512, 2)
void gemm_out2(const short* __restrict__ Ah, const short* __restrict__ Al,
               const short* __restrict__ Bh, const short* __restrict__ Bl,
               float* __restrict__ Cout)
{
    extern __shared__ short L[];            // 32768 shorts = 64 KB
    short* sAh = L;
    short* sAl = L + 8192;
    short* sBh = L + 16384;
    short* sBl = L + 24576;

    const int t = threadIdx.x, w = t >> 6, lane = t & 63;
    const int col = lane & 15, quad = lane >> 4;
    const int wm = w >> 1;
    const int wn = w & 1;

    const int srow = t >> 2;
    const int sko  = ((t & 3) ^ (srow & 3)) * 8;
    const int sdst = t * 8;

    int tid = blockIdx.x;
    int m0 = (tid & 31) * 128, n0 = (tid >> 5) * 128;
    const short* agh = Ah + (size_t)(m0 + srow)*1024 + sko;
    const short* agl = Al + (size_t)(m0 + srow)*1024 + sko;
    const short* bgh = Bh + (size_t)(n0 + srow)*1024 + sko;
    const short* bgl = Bl + (size_t)(n0 + srow)*1024 + sko;

    auto stage = [&](int k0, int pp) {
        gl_lds16(agh + k0, &sAh[pp*4096 + sdst]);
        gl_lds16(agl + k0, &sAl[pp*4096 + sdst]);
        gl_lds16(bgh + k0, &sBh[pp*4096 + sdst]);
        gl_lds16(bgl + k0, &sBl[pp*4096 + sdst]);
    };
    stage(0, 0);
    __syncthreads();

    f4v acc[2][4];
#pragma unroll
    for (int i = 0; i < 2; i++)
#pragma unroll
        for (int j = 0; j < 4; j++) { f4v z = {0.f,0.f,0.f,0.f}; acc[i][j] = z; }

    for (int kt = 0; kt < 32; kt++) {
        const int pp = kt & 1;
        if (kt < 31) stage((kt + 1) * 32, pp ^ 1);

        const int swz = ((quad ^ (col & 3)) << 3);
        s8v bhf[4], blf[4];
#pragma unroll
        for (int j = 0; j < 4; j++) {
            const int boff = pp*4096 + (wn*64 + j*16 + col)*32 + swz;
            bhf[j] = *(const s8v*)&sBh[boff];
            blf[j] = *(const s8v*)&sBl[boff];
        }
#pragma unroll
        for (int i = 0; i < 2; i++) {
            const int aoff = pp*4096 + (wm*32 + i*16 + col)*32 + swz;
            s8v ah = *(const s8v*)&sAh[aoff];
            s8v al = *(const s8v*)&sAl[aoff];
#pragma unroll
            for (int j = 0; j < 4; j++) {
                acc[i][j] = mfma32(ah, bhf[j], acc[i][j]);
                acc[i][j] = mfma32(ah, blf[j], acc[i][j]);
                acc[i][j] = mfma32(al, bhf[j], acc[i][j]);
            }
        }
        __syncthreads();
    }

#pragma unroll
    for (int i = 0; i < 2; i++)
#pragma unroll
    for (int j = 0; j < 4; j++) {
        const int gcol = n0 + wn*64 + j*16 + col;
#pragma unroll
        for (int r = 0; r < 4; r++) {
            const int grow = m0 + wm*32 + i*16 + quad*4 + r;
            Cout[(size_t)grow*1024 + gcol] = acc[i][j][r];
        }
    }
}

// ---------------------------------------------------------------------------
// rowscale[b,q] = 1 / max(max_k dot4(cm[b,:,q], cm[b,:,k]), 1e-6)
// ---------------------------------------------------------------------------
__global__ __launch_bounds__(256)
void rowscale_k(const float* __restrict__ cm, float* __restrict__ rs)
{
    __shared__ float cms[4][2048];
    const int b  = blockIdx.x >> 5;
    const int qt = blockIdx.x & 31;
    const float* base = cm + (size_t)b * 4 * 2048;
    for (int i = threadIdx.x; i < 2048; i += 256) {
        cms[0][i] = base[i];
        cms[1][i] = base[2048 + i];
        cms[2][i] = base[4096 + i];
        cms[3][i] = base[6144 + i];
    }
    __syncthreads();
    const int q    = qt * 64 + (threadIdx.x >> 2);
    const int part = threadIdx.x & 3;
    const float a0 = cms[0][q], a1 = cms[1][q], a2 = cms[2][q], a3 = cms[3][q];
    float mx = 0.f;
    for (int i = 0; i < 512; i++) {
        const int k = part + 4 * i;
        float d = a0*cms[0][k] + a1*cms[1][k] + a2*cms[2][k] + a3*cms[3][k];
        mx = fmaxf(mx, d);
    }
    mx = fmaxf(mx, __shfl_xor(mx, 1));
    mx = fmaxf(mx, __shfl_xor(mx, 2));
    if (part == 0) rs[b * 2048 + q] = 1.0f / fmaxf(mx, 1e-6f);
}

// ---------------------------------------------------------------------------
// Bias precompute, pre-scaled by 3*log2(e) (gate applied in attn):
//  Bias2[b][k>>2][q][k&3] = ((dot4*rsq - 0.5)*2 + 0.3*im) * 3*L2E
// ---------------------------------------------------------------------------
__global__ __launch_bounds__(256)
void bias_pre(const float* __restrict__ cm, const float* __restrict__ im,
              const float* __restrict__ rs, float* __restrict__ Bias2)
{
    const int bid = blockIdx.x;
    const int qq = bid & 15;
    const int kt = (bid >> 4) & 31;
    const int b  = bid >> 9;

    __shared__ float cmk[4][64];
    const int t = threadIdx.x;
    const int k0 = kt * 64;
    cmk[t >> 6][t & 63] = cm[(size_t)b*8192 + (t >> 6)*2048 + k0 + (t & 63)];
    __syncthreads();

    const int klane = t & 15;
    const int qrow  = t >> 4;
    const int kk = k0 + klane*4;
    const int kg = kk >> 2;
    float ck[4][4];
#pragma unroll
    for (int c = 0; c < 4; c++)
#pragma unroll
        for (int j = 0; j < 4; j++) ck[c][j] = cmk[c][klane*4 + j];

    const float* cmb = cm + (size_t)b * 8192;
    const float kS = 3.0f * L2E;
    for (int it = 0; it < 8; it++) {
        const int q = qq*128 + it*16 + qrow;
        float4 imv = *(const float4*)(im + ((size_t)b*2048 + q)*2048 + kk);
        const float rsq = rs[b*2048 + q];
        const float c0 = cmb[q], c1 = cmb[2048+q], c2 = cmb[4096+q], c3 = cmb[6144+q];
        float o[4];
        float iv[4] = {imv.x, imv.y, imv.z, imv.w};
#pragma unroll
        for (int j = 0; j < 4; j++) {
            float same = c0*ck[0][j] + c1*ck[1][j] + c2*ck[2][j] + c3*ck[3][j];
            o[j] = ((same*rsq - 0.5f)*2.0f + 0.3f*iv[j]) * kS;
        }
        *(float4*)(Bias2 + (((size_t)b*512 + kg)*2048 + q)*4) =
            make_float4(o[0], o[1], o[2], o[3]);
    }
}

// ---------------------------------------------------------------------------
// Flash attention, S^T orientation, FP16 datapath.  q-tile 128 (32 q/wave),
// 512 blocks, 2/CU.  QK^T = ONE mfma_f32_16x16x32_f16 term (q/k fp16,
// RMS-normalized -> DS error below P-quantization).  S accumulator is
// initialized to -8 so P = 2^(sr-8) stays inside fp16 range (uniform scale
// cancels in O/li).  P packed fp16 via cvt_pkrtz (2/instr); PV + li MFMAs
// fp16.  K single-plane + V staged by DMA, double-buffered (32 KB static
// LDS), one barrier per tile; bias double-buffered in registers.
// ---------------------------------------------------------------------------
__global__ __launch_bounds__(256, 2)
void attn_mfma(const short* __restrict__ Qp, const short* __restrict__ Kg,
               const short* __restrict__ VtG, const float* __restrict__ Bias2,
               const float* __restrict__ gate, short* __restrict__ Oh,
               short* __restrict__ Ol)
{
    __shared__ __align__(16) short Kbuf[2][64*64];   // [pp][key][d] swz, fp16
    __shared__ __align__(16) short Vbuf[2][64*64];   // [pp][d][sigma-key swz]

    const int bid = blockIdx.x;
    const int h  = bid & 15;
    const int qt = (bid >> 4) & 15;
    const int b  = bid >> 8;

    const int t    = threadIdx.x;
    const int w    = t >> 6;
    const int lane = t & 63;
    const int col  = lane & 15;
    const int quad = lane >> 4;

    const size_t headoff = ((size_t)(b*16 + h)) * 2048 * 64;
    const int qb = qt*128 + w*32;

    // ---- Q B-fragments (fp16, pre-scaled by 0.125*log2(e)) ----
    h8v qf[2][2];
#pragma unroll
    for (int n = 0; n < 2; n++)
#pragma unroll
    for (int c = 0; c < 2; c++) {
        const size_t off = headoff + (size_t)(qb + n*16 + col)*64 + c*32 + quad*8;
        qf[n][c] = *(const h8v*)(Qp + off);
    }

    const float g = fminf(fmaxf(gate[h], 0.f), 1.f);

    h8v ones8;
#pragma unroll
    for (int j = 0; j < 8; j++) ones8[j] = (_Float16)1.0f;

    f4v liacc[2];
    f4v Oa[4][2];
    {
        f4v z = {0.f,0.f,0.f,0.f};
        liacc[0] = z; liacc[1] = z;
#pragma unroll
        for (int dt = 0; dt < 4; dt++)
#pragma unroll
            for (int n = 0; n < 2; n++) Oa[dt][n] = z;
    }

    // ---- staging bases ----
    const short* ksrc = Kg + headoff + (size_t)(w*8 + (lane>>3))*64
                        + ((lane&7) ^ (lane>>3))*8;
    const short* vsrcT = VtG + headoff + (size_t)(w*8 + (lane>>3))*2048
                         + ((lane&7) ^ (lane>>3))*8;

    const float* bptr[2];
#pragma unroll
    for (int n = 0; n < 2; n++)
        bptr[n] = Bias2 + (((size_t)b*512 + quad)*2048 + qb + n*16 + col)*4;

    auto dma = [&](int kbase, int pp) {     // 4 loads/thread
#pragma unroll
        for (int j = 0; j < 2; j++)
            gl_lds16(ksrc + (size_t)kbase*64 + j*2048, &Kbuf[pp][(j*4 + w)*512]);
#pragma unroll
        for (int cc = 0; cc < 2; cc++)
            gl_lds16(vsrcT + (size_t)(kbase + cc*65536), &Vbuf[pp][cc*2048 + w*512]);
    };

    float4 biasA[4][2], biasB[4][2];

    // ---- prologue: tile 0 ----
    dma(0, 0);
#pragma unroll
    for (int s = 0; s < 4; s++)
#pragma unroll
    for (int n = 0; n < 2; n++)
        biasA[s][n] = *(const float4*)(bptr[n] + (size_t)s*4*8192);
    __syncthreads();

    auto tile = [&](int kt, int pp, float4 (&BC)[4][2], float4 (&BN)[4][2]) {
        const int kbase = kt * 64;
        const bool pre = kt < 31;
        if (pre) {
            dma(kbase + 64, pp ^ 1);
#pragma unroll
            for (int s = 0; s < 4; s++)
#pragma unroll
            for (int n = 0; n < 2; n++)
                BN[s][n] = *(const float4*)(bptr[n] +
                    ((size_t)((kbase >> 2) + 16) + s*4)*8192);
        }

        // ---- S^T = K·Q^T - 8  (ONE fp16 term; -8 = fp16 range shift) ----
        f4v S[4][2];
#pragma unroll
        for (int s = 0; s < 4; s++)
#pragma unroll
            for (int n = 0; n < 2; n++) {
                f4v m8 = {-8.f,-8.f,-8.f,-8.f}; S[s][n] = m8;
            }
#pragma unroll
        for (int s = 0; s < 4; s++)
#pragma unroll
        for (int c = 0; c < 2; c++) {
            const int koff = (s*16 + col)*64 + (((c*4 + quad) ^ (col & 7)) << 3);
            h8v kh = *(const h8v*)&Kbuf[pp][koff];
#pragma unroll
            for (int n = 0; n < 2; n++)
                S[s][n] = mfma16f(kh, qf[n][c], S[s][n]);
        }

        // ---- bias (1 FMA) + no-max softmax: p = 2^(S + g*bias - 8) ----
        h8v ph8[2][2];
#pragma unroll
        for (int n = 0; n < 2; n++) {
            union { fp16x2 h2[4]; h8v v; } pk0, pk1;
#pragma unroll
            for (int s = 0; s < 4; s++) {
                const float bb[4] = {BC[s][n].x, BC[s][n].y, BC[s][n].z, BC[s][n].w};
                const float p0 = exp2g(fmaf(bb[0], g, S[s][n][0]));
                const float p1 = exp2g(fmaf(bb[1], g, S[s][n][1]));
                const float p2 = exp2g(fmaf(bb[2], g, S[s][n][2]));
                const float p3 = exp2g(fmaf(bb[3], g, S[s][n][3]));
                fp16x2 u01 = __builtin_amdgcn_cvt_pkrtz(p0, p1);
                fp16x2 u23 = __builtin_amdgcn_cvt_pkrtz(p2, p3);
                if (s < 2) { pk0.h2[s*2] = u01;     pk0.h2[s*2 + 1] = u23; }
                else       { pk1.h2[(s-2)*2] = u01; pk1.h2[(s-2)*2 + 1] = u23; }
            }
            ph8[n][0] = pk0.v;
            ph8[n][1] = pk1.v;
        }

        // ---- li row-sum by MFMA (ones vector; only [0] consumed) ----
#pragma unroll
        for (int n = 0; n < 2; n++)
#pragma unroll
        for (int m = 0; m < 2; m++)
            liacc[n] = mfma16f(ones8, ph8[n][m], liacc[n]);

        // ---- O^T += V^T·P^T  (fp16 16x16x32, conflict-free b128 reads) ----
#pragma unroll
        for (int dt = 0; dt < 4; dt++) {
            const int vrow = (dt*16 + col)*64;
            h8v v0 = *(const h8v*)&Vbuf[pp][vrow + ((((quad*2)    ) ^ (col & 7)) << 3)];
            h8v v1 = *(const h8v*)&Vbuf[pp][vrow + ((((quad*2) + 1) ^ (col & 7)) << 3)];
#pragma unroll
            for (int n = 0; n < 2; n++) {
                Oa[dt][n] = mfma16f(v0, ph8[n][0], Oa[dt][n]);
                Oa[dt][n] = mfma16f(v1, ph8[n][1], Oa[dt][n]);
            }
        }

        if (pre) __syncthreads();   // drains own DMA; all waves done with pp
    };

    for (int kt = 0; kt < 32; kt += 2) {
        tile(kt,     0, biasA, biasB);
        tile(kt + 1, 1, biasB, biasA);
    }

    // ---- epilogue: O^T -> bf16 hi/lo o-planes (B,N,D) ----
#pragma unroll
    for (int n = 0; n < 2; n++) {
        const float inv = 1.0f / liacc[n][0];
        const size_t row = (size_t)b*2048 + qb + n*16 + col;
#pragma unroll
        for (int dt = 0; dt < 4; dt++) {
            s4v hv, lv;
#pragma unroll
            for (int r = 0; r < 4; r++) {
                float y = Oa[dt][n][r] * inv;
                unsigned short hb = f2bf(y);
                hv[r] = (short)hb;
                union { float f; unsigned u; } rr; rr.f = y - bf2f(hb);
                lv[r] = (short)(rr.u >> 16);
            }
            const size_t o = row*1024 + h*64 + dt*16 + quad*4;
            *(s4v*)&Oh[o] = hv;
            *(s4v*)&Ol[o] = lv;
        }
    }
}

// ---------------------------------------------------------------------------
extern "C" void kernel_launch(void* const* d_in, const int* in_sizes, int n_in,
                              void* d_out, int out_size, void* d_ws, size_t ws_size,
                              hipStream_t stream)
{
    const float* x    = (const float*)d_in[0];
    const float* cm   = (const float*)d_in[1];
    const float* im   = (const float*)d_in[2];
    const float* Wqkv = (const float*)d_in[3];
    const float* Wout = (const float*)d_in[4];
    const float* qw   = (const float*)d_in[5];
    const float* kw   = (const float*)d_in[6];
    const float* gate = (const float*)d_in[7];
    float* out = (float*)d_out;

    // ---- workspace layout (bytes) ----
    char* ws = (char*)d_ws;
    short* qp  = (short*)(ws);                    // 8.39 MB fp16 q plane
    short* kp  = (short*)(ws + 16777216);         // 8.39 MB fp16 k plane
    short* vp  = (short*)(ws + 33554432);         // V^T[b,h,d,n'] fp16 (sigma)
    short* oh  = (short*)(ws + 41943040);
    short* ol  = (short*)(ws + 50331648);
    short* woh = (short*)(ws + 58720256);         // 2.10 MB each
    short* wol = (short*)(ws + 60817408);
    float* rsb = (float*)(ws + 62914560);         // 16 KB
    char*  U   = ws + 62930944;                   // union region
    short* xh  = (short*)(U);                     // 8.39 MB (dead after gemm0)
    short* xl  = (short*)(U +  8388608);
    short* wqh = (short*)(U + 16777216);          // 6.29 MB
    short* wql = (short*)(U + 23068672);
    float* bias2 = (float*)(U);                   // 33.55 MB (after gemm0)

    static bool lds_init = false;
    if (!lds_init) {
        (void)hipFuncSetAttribute((const void*)&gemm_qkv2,
                            hipFuncAttributeMaxDynamicSharedMemorySize, 114688);
        (void)hipFuncSetAttribute((const void*)&gemm_out2,
                            hipFuncAttributeMaxDynamicSharedMemorySize, 65536);
        lds_init = true;
    }

    // 1) split inputs into bf16 hi/lo planes
    planes_k<<<4096, 256, 0, stream>>>(x,    xh,  xl);
    planes_k<<<3072, 256, 0, stream>>>(Wqkv, wqh, wql);
    planes_k<<<1024, 256, 0, stream>>>(Wout, woh, wol);
    // 2) qkv projection: 256x192 tiles, 16x16 grid = exactly 1 block/CU
    gemm_qkv2<<<dim3(16, 16), 512, 114688, stream>>>(xh, xl, wqh, wql,
        qp, kp, vp, qw, kw);
    // 3) bias precompute (overwrites x/wq plane region — dead after gemm0)
    rowscale_k<<<64, 256, 0, stream>>>(cm, rsb);
    bias_pre<<<1024, 256, 0, stream>>>(cm, im, rsb, bias2);
    // 4) flash attention (fp16 datapath) -> bf16 o-planes
    attn_mfma<<<512, 256, 0, stream>>>(qp, kp, vp, bias2, gate, oh, ol);
    // 5) output projection: 256 blocks (32x8 tiles of 128^2) -> fp32 out
    gemm_out2<<<256, 512, 65536, stream>>>(oh, ol, woh, wol, out);
}